// Round 9
// baseline (165.614 us; speedup 1.0000x reference)
//
#include <hip/hip_runtime.h>
#include <math.h>

#define N_NODES 50000
#define N_EDGES 800000
#define IN_FEAT 256
#define DIM_H   64
#define NPAD    50176   // padded N slots; 50176 = 392 * 128
#define CAP     48      // per-node capacity; Poisson(16) max deg ~40 << 48
#define NBUK2   1568    // fine dst buckets (32 nodes each)
#define BCAP2   768     // fine-bucket capacity; mean 510, >11 sigma headroom
#define EPB     4096    // edges per binA block
#define PBLKS   784     // proj blocks = 50176/64 (64 rows/block, 2-way K-split waves)
#define ABLKS   196     // binA blocks  = ceil(E/EPB)
#define PNODES  32      // nodes per gather block (= fine bucket size)

typedef __attribute__((ext_vector_type(8)))  short  s16x8;   // 8 bf16 (4 VGPRs)
typedef __attribute__((ext_vector_type(16))) float  f32x16;  // MFMA 32x32 acc

__device__ __forceinline__ short f2bf(float f) {   // RNE f32->bf16
  unsigned u = __float_as_uint(f);
  u += 0x7fffu + ((u >> 16) & 1u);
  return (short)(u >> 16);
}

// ---------------------------------------------------------------------------
// proj_binA r8 (resubmit; r8 bench was an infra failure, kernel never ran):
// B-frags loaded DIRECTLY from global Wsrc into registers (16 frags x 4 VGPR
// = 64 VGPR per K-split wave; VGPR was only 60 in r7, so headroom is ample).
// This deletes:
//  - the 32 KB wfrag LDS staging (LDS 34.3 -> ~20 KB),
//  - its ~2.9M bank-conflict cycles (r7 counter: 64B-stride short stores =
//    32-way write conflict),
//  - one barrier before the MFMA loop,
// and turns the prologue into 128 independent lane-coalesced dword loads
// (L1/L2-hot Wsrc) that pipeline with the 16 x-loads.
// Combine buffer is its own small LDS array, unioned with binA's histogram.
// binA role unchanged (fine-bucket binning).
// ---------------------------------------------------------------------------
__global__ __launch_bounds__(256) void proj_binA_kernel(
    const float* __restrict__ x,
    const float* __restrict__ Wsrc,
    const float* __restrict__ Wdst,
    const float* __restrict__ att_src,
    const float* __restrict__ att_dst,
    const int* __restrict__ ei,
    unsigned* __restrict__ hbf,
    float* __restrict__ a_src,
    float* __restrict__ a_dst,
    int* __restrict__ gbc,
    unsigned* __restrict__ binbuf) {
  __shared__ float cbuf[4672];               // 18.7 KB: K-half combine / binA hist
  __shared__ float wdl[IN_FEAT];             // W_dst @ att_dst
  __shared__ float attl[DIM_H];

  const int tid = threadIdx.x;

  // ---------------- binA role ----------------
  if (blockIdx.x >= PBLKS) {
    int* bcnt = (int*)cbuf;           // overlay: NBUK2 ints
    int* wcur = bcnt + NBUK2;         // overlay: NBUK2 ints (12.5 KB < 18.7 KB)
    const int e0 = (blockIdx.x - PBLKS) * EPB;

    for (int b = tid; b < NBUK2; b += 256) bcnt[b] = 0;
    __syncthreads();

    int dst[16];
    #pragma unroll
    for (int i = 0; i < 16; ++i) {
      int e = e0 + tid + 256 * i;
      dst[i] = (e < N_EDGES) ? ei[N_EDGES + e] : -1;
      if (dst[i] >= 0) atomicAdd(&bcnt[dst[i] >> 5], 1);
    }
    __syncthreads();

    for (int b = tid; b < NBUK2; b += 256) {
      int c = bcnt[b];
      wcur[b] = c ? atomicAdd(&gbc[b], c) : 0;
    }
    __syncthreads();

    #pragma unroll
    for (int i = 0; i < 16; ++i) {
      int e = e0 + tid + 256 * i;
      if (e < N_EDGES) {
        int s = ei[e];
        int b = dst[i] >> 5;
        int pos = atomicAdd(&wcur[b], 1);
        if (pos < BCAP2)
          binbuf[(long)b * BCAP2 + pos] =
              (unsigned)s | ((unsigned)(dst[i] & 31) << 16);
      }
    }
    return;
  }

  // ---------------- proj role ----------------
  const int lane = tid & 63;
  const int wv   = tid >> 6;
  const int tile = wv >> 1;     // which 32-row tile of the block's 64 rows
  const int h    = wv & 1;      // K-half: h=0 -> k 0..127, h=1 -> k 128..255

  if (tid < DIM_H) attl[tid] = att_dst[tid];
  __syncthreads();

  {
    float s = 0.f;
    const float4* row = (const float4*)(Wdst + (long)tid * DIM_H);
    #pragma unroll
    for (int q = 0; q < 16; ++q) {
      float4 r = row[q];
      s = fmaf(r.x, attl[4 * q + 0], s);
      s = fmaf(r.y, attl[4 * q + 1], s);
      s = fmaf(r.z, attl[4 * q + 2], s);
      s = fmaf(r.w, attl[4 * q + 3], s);
    }
    wdl[tid] = s;
  }

  // B-frags direct to registers. Frag (s,t): lane l elem j holds
  // W[k0 + s*16 + (l>>5)*8 + j][(l&31) + 32t]. For fixed (s,t,j) lanes 0-31
  // read consecutive words (128 B coalesced); j walks rows (stride 64 f32).
  s16x8 bfr[16];
  {
    const int kb = h * 128 + (lane >> 5) * 8;
    const int nc = lane & 31;
    #pragma unroll
    for (int s2 = 0; s2 < 8; ++s2) {
      #pragma unroll
      for (int t = 0; t < 2; ++t) {
        const float* wp = Wsrc + (long)(kb + s2 * 16) * DIM_H + nc + 32 * t;
        s16x8 v;
        #pragma unroll
        for (int j = 0; j < 8; ++j) v[j] = f2bf(wp[j * DIM_H]);
        bfr[s2 * 2 + t] = v;
      }
    }
  }
  __syncthreads();   // wdl ready

  const int base  = blockIdx.x * 64 + tile * 32;
  int row = base + (lane & 31); if (row > N_NODES - 1) row = N_NODES - 1;
  const int koff8 = (lane >> 5) * 8;
  const int k0    = h * 128;
  const float* px = x + (long)row * IN_FEAT + k0 + koff8;

  f32x16 acc0, acc1;
  #pragma unroll
  for (int i = 0; i < 16; ++i) { acc0[i] = 0.f; acc1[i] = 0.f; }
  float pd = 0.f;

  #pragma unroll
  for (int s = 0; s < 8; ++s) {
    float4 va = *(const float4*)(px + s * 16);
    float4 vb = *(const float4*)(px + s * 16 + 4);
    const float* wp = wdl + k0 + s * 16 + koff8;
    float4 w1 = *(const float4*)(wp);
    float4 w2 = *(const float4*)(wp + 4);
    pd = fmaf(va.x, w1.x, pd); pd = fmaf(va.y, w1.y, pd);
    pd = fmaf(va.z, w1.z, pd); pd = fmaf(va.w, w1.w, pd);
    pd = fmaf(vb.x, w2.x, pd); pd = fmaf(vb.y, w2.y, pd);
    pd = fmaf(vb.z, w2.z, pd); pd = fmaf(vb.w, w2.w, pd);
    s16x8 a;
    a[0] = f2bf(va.x); a[1] = f2bf(va.y); a[2] = f2bf(va.z); a[3] = f2bf(va.w);
    a[4] = f2bf(vb.x); a[5] = f2bf(vb.y); a[6] = f2bf(vb.z); a[7] = f2bf(vb.w);
    acc0 = __builtin_amdgcn_mfma_f32_32x32x16_bf16(a, bfr[s * 2 + 0], acc0, 0, 0, 0);
    acc1 = __builtin_amdgcn_mfma_f32_32x32x16_bf16(a, bfr[s * 2 + 1], acc1, 0, 0, 0);
  }
  float pds = pd + __shfl_xor(pd, 32, 64);   // lanes<32: row-sum over this K-half

  // ---- K-half combine via cbuf ----
  __syncthreads();
  float* fa = cbuf;
  float* myslot = fa + tile * 2304 + lane * 36;   // stride 36 words: 8-round b128 floor
  float* pdb    = fa + 4608 + tile * 32;          // 2x32 f32 partial a_dst

  if (h == 1) {
    #pragma unroll
    for (int i = 0; i < 4; ++i)
      *(float4*)(myslot + i * 4) =
          make_float4(acc0[4 * i], acc0[4 * i + 1], acc0[4 * i + 2], acc0[4 * i + 3]);
    #pragma unroll
    for (int i = 0; i < 4; ++i)
      *(float4*)(myslot + 16 + i * 4) =
          make_float4(acc1[4 * i], acc1[4 * i + 1], acc1[4 * i + 2], acc1[4 * i + 3]);
    if (lane < 32) pdb[lane] = pds;
  }
  __syncthreads();
  if (h == 1) return;

  #pragma unroll
  for (int i = 0; i < 4; ++i) {
    float4 t = *(const float4*)(myslot + i * 4);
    acc0[4 * i] += t.x; acc0[4 * i + 1] += t.y;
    acc0[4 * i + 2] += t.z; acc0[4 * i + 3] += t.w;
  }
  #pragma unroll
  for (int i = 0; i < 4; ++i) {
    float4 t = *(const float4*)(myslot + 16 + i * 4);
    acc1[4 * i] += t.x; acc1[4 * i + 1] += t.y;
    acc1[4 * i + 2] += t.z; acc1[4 * i + 3] += t.w;
  }
  pds += pdb[lane & 31];

  // ---- epilogue (h=0 waves only; full-K accumulators) ----
  const int col = lane & 31;
  const int rhi = 4 * (lane >> 5);

  #pragma unroll
  for (int r = 0; r < 16; ++r) {
    int node = base + (r & 3) + 8 * (r >> 2) + rhi;
    if (node < N_NODES) {
      unsigned p = (unsigned)(unsigned short)f2bf(acc0[r]) |
                   ((unsigned)(unsigned short)f2bf(acc1[r]) << 16);
      hbf[(long)node * 32 + col] = p;
    }
  }

  float att0 = att_src[col];
  float att1 = att_src[col + 32];
  #pragma unroll
  for (int r = 0; r < 16; ++r) {
    float t = acc0[r] * att0 + acc1[r] * att1;
    t += __shfl_xor(t, 1, 64);
    t += __shfl_xor(t, 2, 64);
    t += __shfl_xor(t, 4, 64);
    t += __shfl_xor(t, 8, 64);
    t += __shfl_xor(t, 16, 64);
    int node = base + (r & 3) + 8 * (r >> 2) + rhi;
    if (col == 0 && node < N_NODES) a_src[node] = t;
  }

  int node = base + (lane & 31);
  if (lane < 32 && node < N_NODES) a_dst[node] = pds;
}

// ---------------------------------------------------------------------------
// gatherfused: IDENTICAL to round-7 (MFMA epilogue version, verified WIN,
// <41.5 us) — frozen so the proj change is cleanly attributable.
// ---------------------------------------------------------------------------
__global__ __launch_bounds__(256) void gatherfused_kernel(
    const unsigned* __restrict__ binbuf,
    const int* __restrict__ gbc,
    const float* __restrict__ a_src,
    const float* __restrict__ a_dst,
    const unsigned* __restrict__ hbf,
    const float* __restrict__ bias_conv,
    const float* __restrict__ W_lin,
    const float* __restrict__ b_lin,
    float* __restrict__ out) {
  __shared__ unsigned rec[PNODES * CAP];   // {bf16(w):16 | src:16}, 6 KB
  __shared__ int   lcnt[PNODES];
  __shared__ float adl[PNODES];
  __shared__ short wlf[4096];              // W_lin B-frags bf16, 8 KB
  __shared__ float hl[PNODES * 68];        // h[32][64] padded stride 68, 8.5 KB

  const int tid    = threadIdx.x;
  const int bucket = blockIdx.x;           // fine bucket = this block's 32 nodes
  const int nb     = bucket * PNODES;      // first node

  // stage W_lin into B-frag order (bf16)
  for (int e4 = tid * 4; e4 < DIM_H * DIM_H; e4 += 1024) {
    float4 w4 = *(const float4*)(W_lin + e4);
    int k = e4 >> 6, n0 = e4 & 63;
    int s = k >> 4, half = (k >> 3) & 1, j = k & 7, t = n0 >> 5;
    short* p = &wlf[((s * 2 + t) * 64 + ((n0 & 31) + 32 * half)) * 8 + j];
    p[0]  = f2bf(w4.x);
    p[8]  = f2bf(w4.y);
    p[16] = f2bf(w4.z);
    p[24] = f2bf(w4.w);
  }
  if (tid < PNODES) {
    lcnt[tid] = 0;
    adl[tid]  = a_dst[nb + tid];   // nodes >= N_NODES never referenced
  }
  __syncthreads();

  // phase 1: bin this bucket's edges into LDS
  int count = gbc[bucket]; if (count > BCAP2) count = BCAP2;
  const unsigned* bb = binbuf + (long)bucket * BCAP2;
  for (int i = tid; i < count; i += 256) {
    unsigned u = bb[i];
    int dl = (int)(u >> 16);               // 0..31
    int s  = (int)(u & 0xffffu);
    float sc = a_src[s] + adl[dl];
    sc = sc >= 0.f ? sc : 0.2f * sc;       // leaky_relu 0.2
    float w = __expf(sc);
    int pos = atomicAdd(&lcnt[dl], 1);
    if (pos < CAP)                         // never fires (maxdeg << CAP)
      rec[dl * CAP + pos] =
          ((unsigned)(unsigned short)f2bf(w) << 16) | (u & 0xffffu);
  }
  __syncthreads();

  // phase 2: gather, pipelined across the wave's 8 nodes
  const int lane = tid & 63;
  const int wv   = __builtin_amdgcn_readfirstlane(tid >> 6);
  const int grp8 = lane >> 3;
  const int ql8  = lane & 7;

  float bcl[4], bch[4];
  #pragma unroll
  for (int c = 0; c < 4; ++c) {
    bcl[c] = bias_conv[ql8 * 4 + c];
    bch[c] = bias_conv[32 + ql8 * 4 + c];
  }

  auto prefetch = [&](int dl, int m_, float& W0, float& W1, uint4& HP0, uint4& HP1) {
    if (m_ > 0) {
      int i0 = (grp8     < m_) ? grp8     : m_ - 1;
      int i1 = (8 + grp8 < m_) ? 8 + grp8 : m_ - 1;
      unsigned u0 = rec[dl * CAP + i0];
      unsigned u1 = rec[dl * CAP + i1];
      W0 = (grp8     < m_) ? __uint_as_float(u0 & 0xffff0000u) : 0.f;
      W1 = (8 + grp8 < m_) ? __uint_as_float(u1 & 0xffff0000u) : 0.f;
      HP0 = *(const uint4*)(hbf + (long)(u0 & 0xffffu) * 32 + ql8 * 4);
      HP1 = *(const uint4*)(hbf + (long)(u1 & 0xffffu) * 32 + ql8 * 4);
    } else {
      W0 = 0.f; W1 = 0.f;
      HP0 = make_uint4(0u, 0u, 0u, 0u);
      HP1 = make_uint4(0u, 0u, 0u, 0u);
    }
  };

  int mcur = lcnt[wv * 8]; if (mcur > CAP) mcur = CAP;
  float pw0, pw1; uint4 php0, php1;
  prefetch(wv * 8, mcur, pw0, pw1, php0, php1);

  #pragma unroll
  for (int q = 0; q < 8; ++q) {
    const int dl = wv * 8 + q;
    const int m  = mcur;

    float alo[4] = {0.f, 0.f, 0.f, 0.f};
    float ahi[4] = {0.f, 0.f, 0.f, 0.f};
    float den = 0.f;

    // consume prefetched trip 1
    {
      alo[0] = fmaf(pw0, __uint_as_float(php0.x << 16),         alo[0]);
      ahi[0] = fmaf(pw0, __uint_as_float(php0.x & 0xffff0000u), ahi[0]);
      alo[1] = fmaf(pw0, __uint_as_float(php0.y << 16),         alo[1]);
      ahi[1] = fmaf(pw0, __uint_as_float(php0.y & 0xffff0000u), ahi[1]);
      alo[2] = fmaf(pw0, __uint_as_float(php0.z << 16),         alo[2]);
      ahi[2] = fmaf(pw0, __uint_as_float(php0.z & 0xffff0000u), ahi[2]);
      alo[3] = fmaf(pw0, __uint_as_float(php0.w << 16),         alo[3]);
      ahi[3] = fmaf(pw0, __uint_as_float(php0.w & 0xffff0000u), ahi[3]);
      den += pw0;
      alo[0] = fmaf(pw1, __uint_as_float(php1.x << 16),         alo[0]);
      ahi[0] = fmaf(pw1, __uint_as_float(php1.x & 0xffff0000u), ahi[0]);
      alo[1] = fmaf(pw1, __uint_as_float(php1.y << 16),         alo[1]);
      ahi[1] = fmaf(pw1, __uint_as_float(php1.y & 0xffff0000u), ahi[1]);
      alo[2] = fmaf(pw1, __uint_as_float(php1.z << 16),         alo[2]);
      ahi[2] = fmaf(pw1, __uint_as_float(php1.z & 0xffff0000u), ahi[2]);
      alo[3] = fmaf(pw1, __uint_as_float(php1.w << 16),         alo[3]);
      ahi[3] = fmaf(pw1, __uint_as_float(php1.w & 0xffff0000u), ahi[3]);
      den += pw1;
    }

    // issue NEXT node's trip-1 before this node's tail + finalize
    if (q < 7) {
      mcur = lcnt[dl + 1]; if (mcur > CAP) mcur = CAP;
      prefetch(dl + 1, mcur, pw0, pw1, php0, php1);
    }

    // tail trips (m > 16)
    for (int j = 16; j < m; j += 16) {
      int idx0 = j + grp8;
      int idx1 = j + 8 + grp8;
      int ci0 = idx0 < m ? idx0 : m - 1;
      int ci1 = idx1 < m ? idx1 : m - 1;
      unsigned u0 = rec[dl * CAP + ci0];
      unsigned u1 = rec[dl * CAP + ci1];
      float w0 = __uint_as_float(u0 & 0xffff0000u);
      float w1 = __uint_as_float(u1 & 0xffff0000u);
      if (idx0 >= m) w0 = 0.f;
      if (idx1 >= m) w1 = 0.f;
      int s0 = (int)(u0 & 0xffffu);
      int s1 = (int)(u1 & 0xffffu);
      uint4 hp0 = *(const uint4*)(hbf + (long)s0 * 32 + ql8 * 4);
      uint4 hp1 = *(const uint4*)(hbf + (long)s1 * 32 + ql8 * 4);
      alo[0] = fmaf(w0, __uint_as_float(hp0.x << 16),         alo[0]);
      ahi[0] = fmaf(w0, __uint_as_float(hp0.x & 0xffff0000u), ahi[0]);
      alo[1] = fmaf(w0, __uint_as_float(hp0.y << 16),         alo[1]);
      ahi[1] = fmaf(w0, __uint_as_float(hp0.y & 0xffff0000u), ahi[1]);
      alo[2] = fmaf(w0, __uint_as_float(hp0.z << 16),         alo[2]);
      ahi[2] = fmaf(w0, __uint_as_float(hp0.z & 0xffff0000u), ahi[2]);
      alo[3] = fmaf(w0, __uint_as_float(hp0.w << 16),         alo[3]);
      ahi[3] = fmaf(w0, __uint_as_float(hp0.w & 0xffff0000u), ahi[3]);
      den += w0;
      alo[0] = fmaf(w1, __uint_as_float(hp1.x << 16),         alo[0]);
      ahi[0] = fmaf(w1, __uint_as_float(hp1.x & 0xffff0000u), ahi[0]);
      alo[1] = fmaf(w1, __uint_as_float(hp1.y << 16),         alo[1]);
      ahi[1] = fmaf(w1, __uint_as_float(hp1.y & 0xffff0000u), ahi[1]);
      alo[2] = fmaf(w1, __uint_as_float(hp1.z << 16),         alo[2]);
      ahi[2] = fmaf(w1, __uint_as_float(hp1.z & 0xffff0000u), ahi[2]);
      alo[3] = fmaf(w1, __uint_as_float(hp1.w << 16),         alo[3]);
      ahi[3] = fmaf(w1, __uint_as_float(hp1.w & 0xffff0000u), ahi[3]);
      den += w1;
    }

    // combine the 8 groups (lanes sharing lane&7 hold the same dims)
    #pragma unroll
    for (int mm = 8; mm <= 32; mm <<= 1) {
      #pragma unroll
      for (int c = 0; c < 4; ++c) {
        alo[c] += __shfl_xor(alo[c], mm, 64);
        ahi[c] += __shfl_xor(ahi[c], mm, 64);
      }
      den += __shfl_xor(den, mm, 64);
    }

    // finalize h for this node: lanes 0-7 each own 8 dims (no transpose)
    if (grp8 == 0) {
      float inv = den > 0.f ? 1.0f / den : 0.f;  // empty segment -> bias only
      float4 hlo, hhi;
      hlo.x = fmaxf(fmaf(alo[0], inv, bcl[0]), 0.f);
      hlo.y = fmaxf(fmaf(alo[1], inv, bcl[1]), 0.f);
      hlo.z = fmaxf(fmaf(alo[2], inv, bcl[2]), 0.f);
      hlo.w = fmaxf(fmaf(alo[3], inv, bcl[3]), 0.f);
      hhi.x = fmaxf(fmaf(ahi[0], inv, bch[0]), 0.f);
      hhi.y = fmaxf(fmaf(ahi[1], inv, bch[1]), 0.f);
      hhi.z = fmaxf(fmaf(ahi[2], inv, bch[2]), 0.f);
      hhi.w = fmaxf(fmaf(ahi[3], inv, bch[3]), 0.f);
      *(float4*)(&hl[dl * 68 + ql8 * 4])      = hlo;
      *(float4*)(&hl[dl * 68 + 32 + ql8 * 4]) = hhi;
    }
  }
  __syncthreads();

  // MFMA epilogue: waves 0/1 compute out[32, 64] = h @ W_lin + b_lin
  if (wv < 2) {
    f32x16 acc;
    #pragma unroll
    for (int i = 0; i < 16; ++i) acc[i] = 0.f;
    const int mrow  = lane & 31;
    const int khalf = (lane >> 5) * 8;
    #pragma unroll
    for (int s = 0; s < 4; ++s) {
      float4 va = *(const float4*)(&hl[mrow * 68 + s * 16 + khalf]);
      float4 vb = *(const float4*)(&hl[mrow * 68 + s * 16 + khalf + 4]);
      s16x8 a;
      a[0] = f2bf(va.x); a[1] = f2bf(va.y); a[2] = f2bf(va.z); a[3] = f2bf(va.w);
      a[4] = f2bf(vb.x); a[5] = f2bf(vb.y); a[6] = f2bf(vb.z); a[7] = f2bf(vb.w);
      s16x8 b = *(const s16x8*)(wlf + ((s * 2 + wv) * 64 + lane) * 8);
      acc = __builtin_amdgcn_mfma_f32_32x32x16_bf16(a, b, acc, 0, 0, 0);
    }
    const int col  = (lane & 31) + 32 * wv;
    const float blv = b_lin[col];
    const int rbase = 4 * (lane >> 5);
    #pragma unroll
    for (int r = 0; r < 16; ++r) {
      int row = (r & 3) + 8 * (r >> 2) + rbase;
      int n = nb + row;
      if (n < N_NODES) out[(long)n * DIM_H + col] = acc[r] + blv;
    }
  }
}

// ---------------------------------------------------------------------------
// Workspace: hbf 6.4 MB | a_src/a_dst 0.4 MB | gbc 8 KB | binbuf 4.8 MB
// ~= 11.6 MB — well under the provided ws.
// ---------------------------------------------------------------------------
extern "C" void kernel_launch(void* const* d_in, const int* in_sizes, int n_in,
                              void* d_out, int out_size, void* d_ws, size_t ws_size,
                              hipStream_t stream) {
  const float* x        = (const float*)d_in[0];
  const int*   ei       = (const int*)d_in[1];
  const float* Wsrc     = (const float*)d_in[2];
  const float* Wdst     = (const float*)d_in[3];
  const float* att_src  = (const float*)d_in[4];
  const float* att_dst  = (const float*)d_in[5];
  const float* bias_cv  = (const float*)d_in[6];
  const float* W_lin    = (const float*)d_in[7];
  const float* b_lin    = (const float*)d_in[8];
  float* out = (float*)d_out;

  unsigned* hbf    = (unsigned*)d_ws;           // N*32 u32 (6.4 MB)
  float*    a_src  = (float*)(hbf + 1600000);   // NPAD f32
  float*    a_dst  = a_src + NPAD;              // NPAD f32
  int*      gbc    = (int*)(a_dst + NPAD);      // 2048 i32 fine-bucket cursors
  unsigned* binbuf = (unsigned*)(gbc + 2048);   // NBUK2*BCAP2 u32 (4.8 MB)

  hipMemsetAsync(gbc, 0, 2048 * sizeof(int), stream);

  proj_binA_kernel<<<PBLKS + ABLKS, 256, 0, stream>>>(
      x, Wsrc, Wdst, att_src, att_dst, ei, hbf, a_src, a_dst, gbc, binbuf);

  gatherfused_kernel<<<NBUK2, 256, 0, stream>>>(
      binbuf, gbc, a_src, a_dst, hbf, bias_cv, W_lin, b_lin, out);
}

// Round 11
// 158.474 us; speedup vs baseline: 1.0451x; 1.0451x over previous
//
#include <hip/hip_runtime.h>
#include <math.h>

#define N_NODES 50000
#define N_EDGES 800000
#define IN_FEAT 256
#define DIM_H   64
#define NPAD    50176   // padded N slots; 50176 = 392 * 128
#define CAP     48      // per-node capacity; Poisson(16) max deg ~40 << 48
#define NBUK2   1568    // fine dst buckets (32 nodes each)
#define BCAP2   768     // fine-bucket capacity; mean 510, >11 sigma headroom
#define EPB     4096    // edges per binA block
#define PBLKS   784     // proj blocks = 50176/64 (64 rows/block, 2-way K-split waves)
#define ABLKS   196     // binA blocks  = ceil(E/EPB)
#define PNODES  32      // nodes per gather block (= fine bucket size)

typedef __attribute__((ext_vector_type(8)))  short  s16x8;   // 8 bf16 (4 VGPRs)
typedef __attribute__((ext_vector_type(16))) float  f32x16;  // MFMA 32x32 acc

__device__ __forceinline__ short f2bf(float f) {   // RNE f32->bf16
  unsigned u = __float_as_uint(f);
  u += 0x7fffu + ((u >> 16) & 1u);
  return (short)(u >> 16);
}

// ---------------------------------------------------------------------------
// proj_binA r11 = r10 with the swizzle-writer bug fixed.
// r10 bug: elements of one float4 stored at sw + {0,16,32,48} (additive) but
// the swizzle is an XOR involution: correct address is sw ^ (i<<4) — addition
// carried into bit 6 whenever sw bits 4-5 != 0, scattering 3/4 of W into
// wrong slots (absmax 40). Writer now XORs; reader unchanged (was already
// XOR-consistent).
// Swizzle recap: slot sidx = frag*64+fl, byte = (sidx<<4) ^ ((sidx&56)<<1);
// staging stores spread over 8 banks (was ~32-way, 2.9M conflict cycles in
// r7); b128 frag reads only permute 16B slots within each 128B window ->
// still the 8-round floor. binA role unchanged.
// ---------------------------------------------------------------------------
__global__ __launch_bounds__(256, 4) void proj_binA_kernel(
    const float* __restrict__ x,
    const float* __restrict__ Wsrc,
    const float* __restrict__ Wdst,
    const float* __restrict__ att_src,
    const float* __restrict__ att_dst,
    const int* __restrict__ ei,
    unsigned* __restrict__ hbf,
    float* __restrict__ a_src,
    float* __restrict__ a_dst,
    int* __restrict__ gbc,
    unsigned* __restrict__ binbuf) {
  __shared__ short wfrag[16 * 2 * 64 * 8];   // 32 KB; overlays: binA hist / combine buf
  __shared__ float wdl[IN_FEAT];             // W_dst @ att_dst
  __shared__ float attl[DIM_H];

  const int tid = threadIdx.x;

  // ---------------- binA role ----------------
  if (blockIdx.x >= PBLKS) {
    int* bcnt = (int*)wfrag;          // overlay: NBUK2 ints
    int* wcur = bcnt + NBUK2;         // overlay: NBUK2 ints (12.5 KB < 32 KB)
    const int e0 = (blockIdx.x - PBLKS) * EPB;

    for (int b = tid; b < NBUK2; b += 256) bcnt[b] = 0;
    __syncthreads();

    int dst[16];
    #pragma unroll
    for (int i = 0; i < 16; ++i) {
      int e = e0 + tid + 256 * i;
      dst[i] = (e < N_EDGES) ? ei[N_EDGES + e] : -1;
      if (dst[i] >= 0) atomicAdd(&bcnt[dst[i] >> 5], 1);
    }
    __syncthreads();

    for (int b = tid; b < NBUK2; b += 256) {
      int c = bcnt[b];
      wcur[b] = c ? atomicAdd(&gbc[b], c) : 0;
    }
    __syncthreads();

    #pragma unroll
    for (int i = 0; i < 16; ++i) {
      int e = e0 + tid + 256 * i;
      if (e < N_EDGES) {
        int s = ei[e];
        int b = dst[i] >> 5;
        int pos = atomicAdd(&wcur[b], 1);
        if (pos < BCAP2)
          binbuf[(long)b * BCAP2 + pos] =
              (unsigned)s | ((unsigned)(dst[i] & 31) << 16);
      }
    }
    return;
  }

  // ---------------- proj role ----------------
  const int lane = tid & 63;
  const int wv   = tid >> 6;
  const int tile = wv >> 1;     // which 32-row tile of the block's 64 rows
  const int h    = wv & 1;      // K-half: h=0 -> k 0..127, h=1 -> k 128..255

  if (tid < DIM_H) attl[tid] = att_dst[tid];
  __syncthreads();

  {
    float s = 0.f;
    const float4* row = (const float4*)(Wdst + (long)tid * DIM_H);
    #pragma unroll
    for (int q = 0; q < 16; ++q) {
      float4 r = row[q];
      s = fmaf(r.x, attl[4 * q + 0], s);
      s = fmaf(r.y, attl[4 * q + 1], s);
      s = fmaf(r.z, attl[4 * q + 2], s);
      s = fmaf(r.w, attl[4 * q + 3], s);
    }
    wdl[tid] = s;
  }

  // stage W_src into B-frag order, float4-vectorized, XOR-swizzled slots.
  // element i of the float4 -> slot sidx+i -> byte sw ^ (i<<4)  (XOR, not +)
  for (int e4 = tid * 4; e4 < IN_FEAT * DIM_H; e4 += 1024) {
    float4 w4 = *(const float4*)(Wsrc + e4);
    int k = e4 >> 6, n0 = e4 & 63;
    int s = k >> 4, half = (k >> 3) & 1, j = k & 7, t = n0 >> 5;
    int fl0  = (n0 & 31) + 32 * half;
    int sidx = (s * 2 + t) * 64 + fl0;
    int sw   = (sidx << 4) ^ ((sidx & 56) << 1);   // swizzled byte offset
    ((short*)((char*)wfrag + (sw ^  0)))[j] = f2bf(w4.x);
    ((short*)((char*)wfrag + (sw ^ 16)))[j] = f2bf(w4.y);
    ((short*)((char*)wfrag + (sw ^ 32)))[j] = f2bf(w4.z);
    ((short*)((char*)wfrag + (sw ^ 48)))[j] = f2bf(w4.w);
  }
  __syncthreads();

  const int base  = blockIdx.x * 64 + tile * 32;
  int row = base + (lane & 31); if (row > N_NODES - 1) row = N_NODES - 1;
  const int koff8 = (lane >> 5) * 8;
  const int k0    = h * 128;
  const float* px = x + (long)row * IN_FEAT + k0 + koff8;
  const int swl   = (lane & 56) << 1;   // reader XOR mask (slot&56 == lane&56)

  f32x16 acc0, acc1;
  #pragma unroll
  for (int i = 0; i < 16; ++i) { acc0[i] = 0.f; acc1[i] = 0.f; }
  float pd = 0.f;

  #pragma unroll
  for (int s = 0; s < 8; ++s) {
    float4 va = *(const float4*)(px + s * 16);
    float4 vb = *(const float4*)(px + s * 16 + 4);
    const float* wp = wdl + k0 + s * 16 + koff8;
    float4 w1 = *(const float4*)(wp);
    float4 w2 = *(const float4*)(wp + 4);
    pd = fmaf(va.x, w1.x, pd); pd = fmaf(va.y, w1.y, pd);
    pd = fmaf(va.z, w1.z, pd); pd = fmaf(va.w, w1.w, pd);
    pd = fmaf(vb.x, w2.x, pd); pd = fmaf(vb.y, w2.y, pd);
    pd = fmaf(vb.z, w2.z, pd); pd = fmaf(vb.w, w2.w, pd);
    s16x8 a;
    a[0] = f2bf(va.x); a[1] = f2bf(va.y); a[2] = f2bf(va.z); a[3] = f2bf(va.w);
    a[4] = f2bf(vb.x); a[5] = f2bf(vb.y); a[6] = f2bf(vb.z); a[7] = f2bf(vb.w);
    const int f = (h * 8 + s) * 2;
    const int si0 = (f + 0) * 64 + lane;
    const int si1 = (f + 1) * 64 + lane;
    s16x8 b0 = *(const s16x8*)((const char*)wfrag + ((si0 << 4) ^ swl));
    s16x8 b1 = *(const s16x8*)((const char*)wfrag + ((si1 << 4) ^ swl));
    acc0 = __builtin_amdgcn_mfma_f32_32x32x16_bf16(a, b0, acc0, 0, 0, 0);
    acc1 = __builtin_amdgcn_mfma_f32_32x32x16_bf16(a, b1, acc1, 0, 0, 0);
  }
  float pds = pd + __shfl_xor(pd, 32, 64);   // lanes<32: row-sum over this K-half

  // ---- K-half combine via LDS overlay of wfrag (raw layout, post-barrier) ----
  __syncthreads();
  float* fa = (float*)wfrag;
  float* myslot = fa + tile * 2304 + lane * 36;   // stride 36 words: 8-round b128 floor
  float* pdb    = fa + 4608 + tile * 32;          // 2x32 f32 partial a_dst

  if (h == 1) {
    #pragma unroll
    for (int i = 0; i < 4; ++i)
      *(float4*)(myslot + i * 4) =
          make_float4(acc0[4 * i], acc0[4 * i + 1], acc0[4 * i + 2], acc0[4 * i + 3]);
    #pragma unroll
    for (int i = 0; i < 4; ++i)
      *(float4*)(myslot + 16 + i * 4) =
          make_float4(acc1[4 * i], acc1[4 * i + 1], acc1[4 * i + 2], acc1[4 * i + 3]);
    if (lane < 32) pdb[lane] = pds;
  }
  __syncthreads();
  if (h == 1) return;

  #pragma unroll
  for (int i = 0; i < 4; ++i) {
    float4 t = *(const float4*)(myslot + i * 4);
    acc0[4 * i] += t.x; acc0[4 * i + 1] += t.y;
    acc0[4 * i + 2] += t.z; acc0[4 * i + 3] += t.w;
  }
  #pragma unroll
  for (int i = 0; i < 4; ++i) {
    float4 t = *(const float4*)(myslot + 16 + i * 4);
    acc1[4 * i] += t.x; acc1[4 * i + 1] += t.y;
    acc1[4 * i + 2] += t.z; acc1[4 * i + 3] += t.w;
  }
  pds += pdb[lane & 31];

  // ---- epilogue (h=0 waves only; full-K accumulators) ----
  const int col = lane & 31;
  const int rhi = 4 * (lane >> 5);

  #pragma unroll
  for (int r = 0; r < 16; ++r) {
    int node = base + (r & 3) + 8 * (r >> 2) + rhi;
    if (node < N_NODES) {
      unsigned p = (unsigned)(unsigned short)f2bf(acc0[r]) |
                   ((unsigned)(unsigned short)f2bf(acc1[r]) << 16);
      hbf[(long)node * 32 + col] = p;
    }
  }

  float att0 = att_src[col];
  float att1 = att_src[col + 32];
  #pragma unroll
  for (int r = 0; r < 16; ++r) {
    float t = acc0[r] * att0 + acc1[r] * att1;
    t += __shfl_xor(t, 1, 64);
    t += __shfl_xor(t, 2, 64);
    t += __shfl_xor(t, 4, 64);
    t += __shfl_xor(t, 8, 64);
    t += __shfl_xor(t, 16, 64);
    int node = base + (r & 3) + 8 * (r >> 2) + rhi;
    if (col == 0 && node < N_NODES) a_src[node] = t;
  }

  int node = base + (lane & 31);
  if (lane < 32 && node < N_NODES) a_dst[node] = pds;
}

// ---------------------------------------------------------------------------
// gatherfused: IDENTICAL to round-7 (MFMA epilogue version, verified WIN,
// <41.5 us) — frozen so the proj change is cleanly attributable.
// ---------------------------------------------------------------------------
__global__ __launch_bounds__(256) void gatherfused_kernel(
    const unsigned* __restrict__ binbuf,
    const int* __restrict__ gbc,
    const float* __restrict__ a_src,
    const float* __restrict__ a_dst,
    const unsigned* __restrict__ hbf,
    const float* __restrict__ bias_conv,
    const float* __restrict__ W_lin,
    const float* __restrict__ b_lin,
    float* __restrict__ out) {
  __shared__ unsigned rec[PNODES * CAP];   // {bf16(w):16 | src:16}, 6 KB
  __shared__ int   lcnt[PNODES];
  __shared__ float adl[PNODES];
  __shared__ short wlf[4096];              // W_lin B-frags bf16, 8 KB
  __shared__ float hl[PNODES * 68];        // h[32][64] padded stride 68, 8.5 KB

  const int tid    = threadIdx.x;
  const int bucket = blockIdx.x;           // fine bucket = this block's 32 nodes
  const int nb     = bucket * PNODES;      // first node

  // stage W_lin into B-frag order (bf16)
  for (int e4 = tid * 4; e4 < DIM_H * DIM_H; e4 += 1024) {
    float4 w4 = *(const float4*)(W_lin + e4);
    int k = e4 >> 6, n0 = e4 & 63;
    int s = k >> 4, half = (k >> 3) & 1, j = k & 7, t = n0 >> 5;
    short* p = &wlf[((s * 2 + t) * 64 + ((n0 & 31) + 32 * half)) * 8 + j];
    p[0]  = f2bf(w4.x);
    p[8]  = f2bf(w4.y);
    p[16] = f2bf(w4.z);
    p[24] = f2bf(w4.w);
  }
  if (tid < PNODES) {
    lcnt[tid] = 0;
    adl[tid]  = a_dst[nb + tid];   // nodes >= N_NODES never referenced
  }
  __syncthreads();

  // phase 1: bin this bucket's edges into LDS
  int count = gbc[bucket]; if (count > BCAP2) count = BCAP2;
  const unsigned* bb = binbuf + (long)bucket * BCAP2;
  for (int i = tid; i < count; i += 256) {
    unsigned u = bb[i];
    int dl = (int)(u >> 16);               // 0..31
    int s  = (int)(u & 0xffffu);
    float sc = a_src[s] + adl[dl];
    sc = sc >= 0.f ? sc : 0.2f * sc;       // leaky_relu 0.2
    float w = __expf(sc);
    int pos = atomicAdd(&lcnt[dl], 1);
    if (pos < CAP)                         // never fires (maxdeg << CAP)
      rec[dl * CAP + pos] =
          ((unsigned)(unsigned short)f2bf(w) << 16) | (u & 0xffffu);
  }
  __syncthreads();

  // phase 2: gather, pipelined across the wave's 8 nodes
  const int lane = tid & 63;
  const int wv   = __builtin_amdgcn_readfirstlane(tid >> 6);
  const int grp8 = lane >> 3;
  const int ql8  = lane & 7;

  float bcl[4], bch[4];
  #pragma unroll
  for (int c = 0; c < 4; ++c) {
    bcl[c] = bias_conv[ql8 * 4 + c];
    bch[c] = bias_conv[32 + ql8 * 4 + c];
  }

  auto prefetch = [&](int dl, int m_, float& W0, float& W1, uint4& HP0, uint4& HP1) {
    if (m_ > 0) {
      int i0 = (grp8     < m_) ? grp8     : m_ - 1;
      int i1 = (8 + grp8 < m_) ? 8 + grp8 : m_ - 1;
      unsigned u0 = rec[dl * CAP + i0];
      unsigned u1 = rec[dl * CAP + i1];
      W0 = (grp8     < m_) ? __uint_as_float(u0 & 0xffff0000u) : 0.f;
      W1 = (8 + grp8 < m_) ? __uint_as_float(u1 & 0xffff0000u) : 0.f;
      HP0 = *(const uint4*)(hbf + (long)(u0 & 0xffffu) * 32 + ql8 * 4);
      HP1 = *(const uint4*)(hbf + (long)(u1 & 0xffffu) * 32 + ql8 * 4);
    } else {
      W0 = 0.f; W1 = 0.f;
      HP0 = make_uint4(0u, 0u, 0u, 0u);
      HP1 = make_uint4(0u, 0u, 0u, 0u);
    }
  };

  int mcur = lcnt[wv * 8]; if (mcur > CAP) mcur = CAP;
  float pw0, pw1; uint4 php0, php1;
  prefetch(wv * 8, mcur, pw0, pw1, php0, php1);

  #pragma unroll
  for (int q = 0; q < 8; ++q) {
    const int dl = wv * 8 + q;
    const int m  = mcur;

    float alo[4] = {0.f, 0.f, 0.f, 0.f};
    float ahi[4] = {0.f, 0.f, 0.f, 0.f};
    float den = 0.f;

    // consume prefetched trip 1
    {
      alo[0] = fmaf(pw0, __uint_as_float(php0.x << 16),         alo[0]);
      ahi[0] = fmaf(pw0, __uint_as_float(php0.x & 0xffff0000u), ahi[0]);
      alo[1] = fmaf(pw0, __uint_as_float(php0.y << 16),         alo[1]);
      ahi[1] = fmaf(pw0, __uint_as_float(php0.y & 0xffff0000u), ahi[1]);
      alo[2] = fmaf(pw0, __uint_as_float(php0.z << 16),         alo[2]);
      ahi[2] = fmaf(pw0, __uint_as_float(php0.z & 0xffff0000u), ahi[2]);
      alo[3] = fmaf(pw0, __uint_as_float(php0.w << 16),         alo[3]);
      ahi[3] = fmaf(pw0, __uint_as_float(php0.w & 0xffff0000u), ahi[3]);
      den += pw0;
      alo[0] = fmaf(pw1, __uint_as_float(php1.x << 16),         alo[0]);
      ahi[0] = fmaf(pw1, __uint_as_float(php1.x & 0xffff0000u), ahi[0]);
      alo[1] = fmaf(pw1, __uint_as_float(php1.y << 16),         alo[1]);
      ahi[1] = fmaf(pw1, __uint_as_float(php1.y & 0xffff0000u), ahi[1]);
      alo[2] = fmaf(pw1, __uint_as_float(php1.z << 16),         alo[2]);
      ahi[2] = fmaf(pw1, __uint_as_float(php1.z & 0xffff0000u), ahi[2]);
      alo[3] = fmaf(pw1, __uint_as_float(php1.w << 16),         alo[3]);
      ahi[3] = fmaf(pw1, __uint_as_float(php1.w & 0xffff0000u), ahi[3]);
      den += pw1;
    }

    // issue NEXT node's trip-1 before this node's tail + finalize
    if (q < 7) {
      mcur = lcnt[dl + 1]; if (mcur > CAP) mcur = CAP;
      prefetch(dl + 1, mcur, pw0, pw1, php0, php1);
    }

    // tail trips (m > 16)
    for (int j = 16; j < m; j += 16) {
      int idx0 = j + grp8;
      int idx1 = j + 8 + grp8;
      int ci0 = idx0 < m ? idx0 : m - 1;
      int ci1 = idx1 < m ? idx1 : m - 1;
      unsigned u0 = rec[dl * CAP + ci0];
      unsigned u1 = rec[dl * CAP + ci1];
      float w0 = __uint_as_float(u0 & 0xffff0000u);
      float w1 = __uint_as_float(u1 & 0xffff0000u);
      if (idx0 >= m) w0 = 0.f;
      if (idx1 >= m) w1 = 0.f;
      int s0 = (int)(u0 & 0xffffu);
      int s1 = (int)(u1 & 0xffffu);
      uint4 hp0 = *(const uint4*)(hbf + (long)s0 * 32 + ql8 * 4);
      uint4 hp1 = *(const uint4*)(hbf + (long)s1 * 32 + ql8 * 4);
      alo[0] = fmaf(w0, __uint_as_float(hp0.x << 16),         alo[0]);
      ahi[0] = fmaf(w0, __uint_as_float(hp0.x & 0xffff0000u), ahi[0]);
      alo[1] = fmaf(w0, __uint_as_float(hp0.y << 16),         alo[1]);
      ahi[1] = fmaf(w0, __uint_as_float(hp0.y & 0xffff0000u), ahi[1]);
      alo[2] = fmaf(w0, __uint_as_float(hp0.z << 16),         alo[2]);
      ahi[2] = fmaf(w0, __uint_as_float(hp0.z & 0xffff0000u), ahi[2]);
      alo[3] = fmaf(w0, __uint_as_float(hp0.w << 16),         alo[3]);
      ahi[3] = fmaf(w0, __uint_as_float(hp0.w & 0xffff0000u), ahi[3]);
      den += w0;
      alo[0] = fmaf(w1, __uint_as_float(hp1.x << 16),         alo[0]);
      ahi[0] = fmaf(w1, __uint_as_float(hp1.x & 0xffff0000u), ahi[0]);
      alo[1] = fmaf(w1, __uint_as_float(hp1.y << 16),         alo[1]);
      ahi[1] = fmaf(w1, __uint_as_float(hp1.y & 0xffff0000u), ahi[1]);
      alo[2] = fmaf(w1, __uint_as_float(hp1.z << 16),         alo[2]);
      ahi[2] = fmaf(w1, __uint_as_float(hp1.z & 0xffff0000u), ahi[2]);
      alo[3] = fmaf(w1, __uint_as_float(hp1.w << 16),         alo[3]);
      ahi[3] = fmaf(w1, __uint_as_float(hp1.w & 0xffff0000u), ahi[3]);
      den += w1;
    }

    // combine the 8 groups (lanes sharing lane&7 hold the same dims)
    #pragma unroll
    for (int mm = 8; mm <= 32; mm <<= 1) {
      #pragma unroll
      for (int c = 0; c < 4; ++c) {
        alo[c] += __shfl_xor(alo[c], mm, 64);
        ahi[c] += __shfl_xor(ahi[c], mm, 64);
      }
      den += __shfl_xor(den, mm, 64);
    }

    // finalize h for this node: lanes 0-7 each own 8 dims (no transpose)
    if (grp8 == 0) {
      float inv = den > 0.f ? 1.0f / den : 0.f;  // empty segment -> bias only
      float4 hlo, hhi;
      hlo.x = fmaxf(fmaf(alo[0], inv, bcl[0]), 0.f);
      hlo.y = fmaxf(fmaf(alo[1], inv, bcl[1]), 0.f);
      hlo.z = fmaxf(fmaf(alo[2], inv, bcl[2]), 0.f);
      hlo.w = fmaxf(fmaf(alo[3], inv, bcl[3]), 0.f);
      hhi.x = fmaxf(fmaf(ahi[0], inv, bch[0]), 0.f);
      hhi.y = fmaxf(fmaf(ahi[1], inv, bch[1]), 0.f);
      hhi.z = fmaxf(fmaf(ahi[2], inv, bch[2]), 0.f);
      hhi.w = fmaxf(fmaf(ahi[3], inv, bch[3]), 0.f);
      *(float4*)(&hl[dl * 68 + ql8 * 4])      = hlo;
      *(float4*)(&hl[dl * 68 + 32 + ql8 * 4]) = hhi;
    }
  }
  __syncthreads();

  // MFMA epilogue: waves 0/1 compute out[32, 64] = h @ W_lin + b_lin
  if (wv < 2) {
    f32x16 acc;
    #pragma unroll
    for (int i = 0; i < 16; ++i) acc[i] = 0.f;
    const int mrow  = lane & 31;
    const int khalf = (lane >> 5) * 8;
    #pragma unroll
    for (int s = 0; s < 4; ++s) {
      float4 va = *(const float4*)(&hl[mrow * 68 + s * 16 + khalf]);
      float4 vb = *(const float4*)(&hl[mrow * 68 + s * 16 + khalf + 4]);
      s16x8 a;
      a[0] = f2bf(va.x); a[1] = f2bf(va.y); a[2] = f2bf(va.z); a[3] = f2bf(va.w);
      a[4] = f2bf(vb.x); a[5] = f2bf(vb.y); a[6] = f2bf(vb.z); a[7] = f2bf(vb.w);
      s16x8 b = *(const s16x8*)(wlf + ((s * 2 + wv) * 64 + lane) * 8);
      acc = __builtin_amdgcn_mfma_f32_32x32x16_bf16(a, b, acc, 0, 0, 0);
    }
    const int col  = (lane & 31) + 32 * wv;
    const float blv = b_lin[col];
    const int rbase = 4 * (lane >> 5);
    #pragma unroll
    for (int r = 0; r < 16; ++r) {
      int row = (r & 3) + 8 * (r >> 2) + rbase;
      int n = nb + row;
      if (n < N_NODES) out[(long)n * DIM_H + col] = acc[r] + blv;
    }
  }
}

// ---------------------------------------------------------------------------
// Workspace: hbf 6.4 MB | a_src/a_dst 0.4 MB | gbc 8 KB | binbuf 4.8 MB
// ~= 11.6 MB — well under the provided ws.
// ---------------------------------------------------------------------------
extern "C" void kernel_launch(void* const* d_in, const int* in_sizes, int n_in,
                              void* d_out, int out_size, void* d_ws, size_t ws_size,
                              hipStream_t stream) {
  const float* x        = (const float*)d_in[0];
  const int*   ei       = (const int*)d_in[1];
  const float* Wsrc     = (const float*)d_in[2];
  const float* Wdst     = (const float*)d_in[3];
  const float* att_src  = (const float*)d_in[4];
  const float* att_dst  = (const float*)d_in[5];
  const float* bias_cv  = (const float*)d_in[6];
  const float* W_lin    = (const float*)d_in[7];
  const float* b_lin    = (const float*)d_in[8];
  float* out = (float*)d_out;

  unsigned* hbf    = (unsigned*)d_ws;           // N*32 u32 (6.4 MB)
  float*    a_src  = (float*)(hbf + 1600000);   // NPAD f32
  float*    a_dst  = a_src + NPAD;              // NPAD f32
  int*      gbc    = (int*)(a_dst + NPAD);      // 2048 i32 fine-bucket cursors
  unsigned* binbuf = (unsigned*)(gbc + 2048);   // NBUK2*BCAP2 u32 (4.8 MB)

  hipMemsetAsync(gbc, 0, 2048 * sizeof(int), stream);

  proj_binA_kernel<<<PBLKS + ABLKS, 256, 0, stream>>>(
      x, Wsrc, Wdst, att_src, att_dst, ei, hbf, a_src, a_dst, gbc, binbuf);

  gatherfused_kernel<<<NBUK2, 256, 0, stream>>>(
      binbuf, gbc, a_src, a_dst, hbf, bias_cv, W_lin, b_lin, out);
}

// Round 12
// 156.540 us; speedup vs baseline: 1.0580x; 1.0124x over previous
//
#include <hip/hip_runtime.h>
#include <math.h>

#define N_NODES 50000
#define N_EDGES 800000
#define IN_FEAT 256
#define DIM_H   64
#define NPAD    50176   // padded N slots; 50176 = 392 * 128
#define CAP     48      // per-node capacity; Poisson(16) max deg ~40 << 48
#define NBUK2   1568    // fine dst buckets (32 nodes each)
#define BCAP2   768     // fine-bucket capacity; mean 510, >11 sigma headroom
#define EPB     4096    // edges per binA block
#define PBLKS   392     // proj blocks = 50176/128 (128 rows/block, 8 waves)
#define ABLKS   196     // binA blocks  = ceil(E/EPB)
#define PNODES  32      // nodes per gather block (= fine bucket size)

typedef __attribute__((ext_vector_type(8)))  short  s16x8;   // 8 bf16 (4 VGPRs)
typedef __attribute__((ext_vector_type(16))) float  f32x16;  // MFMA 32x32 acc

__device__ __forceinline__ short f2bf(float f) {   // RNE f32->bf16
  unsigned u = __float_as_uint(f);
  u += 0x7fffu + ((u >> 16) & 1u);
  return (short)(u >> 16);
}

// ---------------------------------------------------------------------------
// proj_binA r12: 512-thread proj blocks — 128 rows = 4 tiles x 2 K-halves.
// r11 counters (Occ 25%, VALU 11%, HBM 14%, all low) = latency-bound and
// occupancy-capped: LDS 34.3KB -> 4 blk/CU x 4 waves = 16 waves/CU, and the
// 32KB W-frag prologue was re-staged by all 784 blocks (~35% of proj time,
// r4/r5 data; r6: separate prep dispatch loses to the serial bubble; r9:
// per-wave reg frags lose to redundant converts). 8-wave blocks halve the
// prologue count (392 stagings) and raise the wave ceiling to 32/CU at 4
// blk/CU (needs VGPR<=64; body unchanged from the 64-VGPR r11 kernel,
// launch_bounds(512,4) caps at 128 like r7's proven config).
// Combine buffer: 4 tiles x 2304 f32 + 128 pdb = 9344 f32 (37.4KB), unioned
// with the 32KB wfrag (union = fa[9344]) -> LDS ~38.7KB -> 4 blk/CU.
// W staging keeps r11's verified XOR swizzle (conflicts 2.9M -> 528K).
// binA: same fine-bucket binning, 8 edges/thread x 8 iters at 512 threads.
// ---------------------------------------------------------------------------
__global__ __launch_bounds__(512, 4) void proj_binA_kernel(
    const float* __restrict__ x,
    const float* __restrict__ Wsrc,
    const float* __restrict__ Wdst,
    const float* __restrict__ att_src,
    const float* __restrict__ att_dst,
    const int* __restrict__ ei,
    unsigned* __restrict__ hbf,
    float* __restrict__ a_src,
    float* __restrict__ a_dst,
    int* __restrict__ gbc,
    unsigned* __restrict__ binbuf) {
  __shared__ float fa[9344];                 // 37.4 KB: wfrag overlay / combine / binA hist
  __shared__ float wdl[IN_FEAT];             // W_dst @ att_dst
  __shared__ float attl[DIM_H];

  short* const wfrag = (short*)fa;           // 16384 bf16 = first 8192 f32 words
  const int tid = threadIdx.x;

  // ---------------- binA role ----------------
  if (blockIdx.x >= PBLKS) {
    int* bcnt = (int*)fa;             // overlay: NBUK2 ints
    int* wcur = bcnt + NBUK2;         // overlay: NBUK2 ints (12.5 KB < 37.4 KB)
    const int e0 = (blockIdx.x - PBLKS) * EPB;

    for (int b = tid; b < NBUK2; b += 512) bcnt[b] = 0;
    __syncthreads();

    int dst[8];
    #pragma unroll
    for (int i = 0; i < 8; ++i) {
      int e = e0 + tid + 512 * i;
      dst[i] = (e < N_EDGES) ? ei[N_EDGES + e] : -1;
      if (dst[i] >= 0) atomicAdd(&bcnt[dst[i] >> 5], 1);
    }
    __syncthreads();

    for (int b = tid; b < NBUK2; b += 512) {
      int c = bcnt[b];
      wcur[b] = c ? atomicAdd(&gbc[b], c) : 0;
    }
    __syncthreads();

    #pragma unroll
    for (int i = 0; i < 8; ++i) {
      int e = e0 + tid + 512 * i;
      if (e < N_EDGES) {
        int s = ei[e];
        int b = dst[i] >> 5;
        int pos = atomicAdd(&wcur[b], 1);
        if (pos < BCAP2)
          binbuf[(long)b * BCAP2 + pos] =
              (unsigned)s | ((unsigned)(dst[i] & 31) << 16);
      }
    }
    return;
  }

  // ---------------- proj role ----------------
  const int lane = tid & 63;
  const int wv   = tid >> 6;    // 0..7
  const int tile = wv >> 1;     // which 32-row tile of the block's 128 rows
  const int h    = wv & 1;      // K-half: h=0 -> k 0..127, h=1 -> k 128..255

  if (tid < DIM_H) attl[tid] = att_dst[tid];
  __syncthreads();

  if (tid < IN_FEAT) {
    float s = 0.f;
    const float4* row = (const float4*)(Wdst + (long)tid * DIM_H);
    #pragma unroll
    for (int q = 0; q < 16; ++q) {
      float4 r = row[q];
      s = fmaf(r.x, attl[4 * q + 0], s);
      s = fmaf(r.y, attl[4 * q + 1], s);
      s = fmaf(r.z, attl[4 * q + 2], s);
      s = fmaf(r.w, attl[4 * q + 3], s);
    }
    wdl[tid] = s;
  }

  // stage W_src into B-frag order, float4-vectorized, XOR-swizzled slots.
  // element i of the float4 -> slot sidx+i -> byte sw ^ (i<<4)
  for (int e4 = tid * 4; e4 < IN_FEAT * DIM_H; e4 += 2048) {
    float4 w4 = *(const float4*)(Wsrc + e4);
    int k = e4 >> 6, n0 = e4 & 63;
    int s = k >> 4, half = (k >> 3) & 1, j = k & 7, t = n0 >> 5;
    int fl0  = (n0 & 31) + 32 * half;
    int sidx = (s * 2 + t) * 64 + fl0;
    int sw   = (sidx << 4) ^ ((sidx & 56) << 1);   // swizzled byte offset
    ((short*)((char*)wfrag + (sw ^  0)))[j] = f2bf(w4.x);
    ((short*)((char*)wfrag + (sw ^ 16)))[j] = f2bf(w4.y);
    ((short*)((char*)wfrag + (sw ^ 32)))[j] = f2bf(w4.z);
    ((short*)((char*)wfrag + (sw ^ 48)))[j] = f2bf(w4.w);
  }
  __syncthreads();

  const int base  = blockIdx.x * 128 + tile * 32;
  int row = base + (lane & 31); if (row > N_NODES - 1) row = N_NODES - 1;
  const int koff8 = (lane >> 5) * 8;
  const int k0    = h * 128;
  const float* px = x + (long)row * IN_FEAT + k0 + koff8;
  const int swl   = (lane & 56) << 1;   // reader XOR mask (slot&56 == lane&56)

  f32x16 acc0, acc1;
  #pragma unroll
  for (int i = 0; i < 16; ++i) { acc0[i] = 0.f; acc1[i] = 0.f; }
  float pd = 0.f;

  #pragma unroll
  for (int s = 0; s < 8; ++s) {
    float4 va = *(const float4*)(px + s * 16);
    float4 vb = *(const float4*)(px + s * 16 + 4);
    const float* wp = wdl + k0 + s * 16 + koff8;
    float4 w1 = *(const float4*)(wp);
    float4 w2 = *(const float4*)(wp + 4);
    pd = fmaf(va.x, w1.x, pd); pd = fmaf(va.y, w1.y, pd);
    pd = fmaf(va.z, w1.z, pd); pd = fmaf(va.w, w1.w, pd);
    pd = fmaf(vb.x, w2.x, pd); pd = fmaf(vb.y, w2.y, pd);
    pd = fmaf(vb.z, w2.z, pd); pd = fmaf(vb.w, w2.w, pd);
    s16x8 a;
    a[0] = f2bf(va.x); a[1] = f2bf(va.y); a[2] = f2bf(va.z); a[3] = f2bf(va.w);
    a[4] = f2bf(vb.x); a[5] = f2bf(vb.y); a[6] = f2bf(vb.z); a[7] = f2bf(vb.w);
    const int f = (h * 8 + s) * 2;
    const int si0 = (f + 0) * 64 + lane;
    const int si1 = (f + 1) * 64 + lane;
    s16x8 b0 = *(const s16x8*)((const char*)wfrag + ((si0 << 4) ^ swl));
    s16x8 b1 = *(const s16x8*)((const char*)wfrag + ((si1 << 4) ^ swl));
    acc0 = __builtin_amdgcn_mfma_f32_32x32x16_bf16(a, b0, acc0, 0, 0, 0);
    acc1 = __builtin_amdgcn_mfma_f32_32x32x16_bf16(a, b1, acc1, 0, 0, 0);
  }
  float pds = pd + __shfl_xor(pd, 32, 64);   // lanes<32: row-sum over this K-half

  // ---- K-half combine via fa (wfrag dead after MFMA loop) ----
  __syncthreads();
  float* myslot = fa + tile * 2304 + lane * 36;   // stride 36 words: 8-round b128 floor
  float* pdb    = fa + 9216 + tile * 32;          // 4x32 f32 partial a_dst

  if (h == 1) {
    #pragma unroll
    for (int i = 0; i < 4; ++i)
      *(float4*)(myslot + i * 4) =
          make_float4(acc0[4 * i], acc0[4 * i + 1], acc0[4 * i + 2], acc0[4 * i + 3]);
    #pragma unroll
    for (int i = 0; i < 4; ++i)
      *(float4*)(myslot + 16 + i * 4) =
          make_float4(acc1[4 * i], acc1[4 * i + 1], acc1[4 * i + 2], acc1[4 * i + 3]);
    if (lane < 32) pdb[lane] = pds;
  }
  __syncthreads();
  if (h == 1) return;

  #pragma unroll
  for (int i = 0; i < 4; ++i) {
    float4 t = *(const float4*)(myslot + i * 4);
    acc0[4 * i] += t.x; acc0[4 * i + 1] += t.y;
    acc0[4 * i + 2] += t.z; acc0[4 * i + 3] += t.w;
  }
  #pragma unroll
  for (int i = 0; i < 4; ++i) {
    float4 t = *(const float4*)(myslot + 16 + i * 4);
    acc1[4 * i] += t.x; acc1[4 * i + 1] += t.y;
    acc1[4 * i + 2] += t.z; acc1[4 * i + 3] += t.w;
  }
  pds += pdb[lane & 31];

  // ---- epilogue (h=0 waves only; full-K accumulators) ----
  const int col = lane & 31;
  const int rhi = 4 * (lane >> 5);

  #pragma unroll
  for (int r = 0; r < 16; ++r) {
    int node = base + (r & 3) + 8 * (r >> 2) + rhi;
    if (node < N_NODES) {
      unsigned p = (unsigned)(unsigned short)f2bf(acc0[r]) |
                   ((unsigned)(unsigned short)f2bf(acc1[r]) << 16);
      hbf[(long)node * 32 + col] = p;
    }
  }

  float att0 = att_src[col];
  float att1 = att_src[col + 32];
  #pragma unroll
  for (int r = 0; r < 16; ++r) {
    float t = acc0[r] * att0 + acc1[r] * att1;
    t += __shfl_xor(t, 1, 64);
    t += __shfl_xor(t, 2, 64);
    t += __shfl_xor(t, 4, 64);
    t += __shfl_xor(t, 8, 64);
    t += __shfl_xor(t, 16, 64);
    int node = base + (r & 3) + 8 * (r >> 2) + rhi;
    if (col == 0 && node < N_NODES) a_src[node] = t;
  }

  int node = base + (lane & 31);
  if (lane < 32 && node < N_NODES) a_dst[node] = pds;
}

// ---------------------------------------------------------------------------
// gatherfused: IDENTICAL to round-7/r11 (MFMA epilogue version, verified WIN,
// <41.5 us) — frozen so the proj change is cleanly attributable.
// ---------------------------------------------------------------------------
__global__ __launch_bounds__(256) void gatherfused_kernel(
    const unsigned* __restrict__ binbuf,
    const int* __restrict__ gbc,
    const float* __restrict__ a_src,
    const float* __restrict__ a_dst,
    const unsigned* __restrict__ hbf,
    const float* __restrict__ bias_conv,
    const float* __restrict__ W_lin,
    const float* __restrict__ b_lin,
    float* __restrict__ out) {
  __shared__ unsigned rec[PNODES * CAP];   // {bf16(w):16 | src:16}, 6 KB
  __shared__ int   lcnt[PNODES];
  __shared__ float adl[PNODES];
  __shared__ short wlf[4096];              // W_lin B-frags bf16, 8 KB
  __shared__ float hl[PNODES * 68];        // h[32][64] padded stride 68, 8.5 KB

  const int tid    = threadIdx.x;
  const int bucket = blockIdx.x;           // fine bucket = this block's 32 nodes
  const int nb     = bucket * PNODES;      // first node

  // stage W_lin into B-frag order (bf16)
  for (int e4 = tid * 4; e4 < DIM_H * DIM_H; e4 += 1024) {
    float4 w4 = *(const float4*)(W_lin + e4);
    int k = e4 >> 6, n0 = e4 & 63;
    int s = k >> 4, half = (k >> 3) & 1, j = k & 7, t = n0 >> 5;
    short* p = &wlf[((s * 2 + t) * 64 + ((n0 & 31) + 32 * half)) * 8 + j];
    p[0]  = f2bf(w4.x);
    p[8]  = f2bf(w4.y);
    p[16] = f2bf(w4.z);
    p[24] = f2bf(w4.w);
  }
  if (tid < PNODES) {
    lcnt[tid] = 0;
    adl[tid]  = a_dst[nb + tid];   // nodes >= N_NODES never referenced
  }
  __syncthreads();

  // phase 1: bin this bucket's edges into LDS
  int count = gbc[bucket]; if (count > BCAP2) count = BCAP2;
  const unsigned* bb = binbuf + (long)bucket * BCAP2;
  for (int i = tid; i < count; i += 256) {
    unsigned u = bb[i];
    int dl = (int)(u >> 16);               // 0..31
    int s  = (int)(u & 0xffffu);
    float sc = a_src[s] + adl[dl];
    sc = sc >= 0.f ? sc : 0.2f * sc;       // leaky_relu 0.2
    float w = __expf(sc);
    int pos = atomicAdd(&lcnt[dl], 1);
    if (pos < CAP)                         // never fires (maxdeg << CAP)
      rec[dl * CAP + pos] =
          ((unsigned)(unsigned short)f2bf(w) << 16) | (u & 0xffffu);
  }
  __syncthreads();

  // phase 2: gather, pipelined across the wave's 8 nodes
  const int lane = tid & 63;
  const int wv   = __builtin_amdgcn_readfirstlane(tid >> 6);
  const int grp8 = lane >> 3;
  const int ql8  = lane & 7;

  float bcl[4], bch[4];
  #pragma unroll
  for (int c = 0; c < 4; ++c) {
    bcl[c] = bias_conv[ql8 * 4 + c];
    bch[c] = bias_conv[32 + ql8 * 4 + c];
  }

  auto prefetch = [&](int dl, int m_, float& W0, float& W1, uint4& HP0, uint4& HP1) {
    if (m_ > 0) {
      int i0 = (grp8     < m_) ? grp8     : m_ - 1;
      int i1 = (8 + grp8 < m_) ? 8 + grp8 : m_ - 1;
      unsigned u0 = rec[dl * CAP + i0];
      unsigned u1 = rec[dl * CAP + i1];
      W0 = (grp8     < m_) ? __uint_as_float(u0 & 0xffff0000u) : 0.f;
      W1 = (8 + grp8 < m_) ? __uint_as_float(u1 & 0xffff0000u) : 0.f;
      HP0 = *(const uint4*)(hbf + (long)(u0 & 0xffffu) * 32 + ql8 * 4);
      HP1 = *(const uint4*)(hbf + (long)(u1 & 0xffffu) * 32 + ql8 * 4);
    } else {
      W0 = 0.f; W1 = 0.f;
      HP0 = make_uint4(0u, 0u, 0u, 0u);
      HP1 = make_uint4(0u, 0u, 0u, 0u);
    }
  };

  int mcur = lcnt[wv * 8]; if (mcur > CAP) mcur = CAP;
  float pw0, pw1; uint4 php0, php1;
  prefetch(wv * 8, mcur, pw0, pw1, php0, php1);

  #pragma unroll
  for (int q = 0; q < 8; ++q) {
    const int dl = wv * 8 + q;
    const int m  = mcur;

    float alo[4] = {0.f, 0.f, 0.f, 0.f};
    float ahi[4] = {0.f, 0.f, 0.f, 0.f};
    float den = 0.f;

    // consume prefetched trip 1
    {
      alo[0] = fmaf(pw0, __uint_as_float(php0.x << 16),         alo[0]);
      ahi[0] = fmaf(pw0, __uint_as_float(php0.x & 0xffff0000u), ahi[0]);
      alo[1] = fmaf(pw0, __uint_as_float(php0.y << 16),         alo[1]);
      ahi[1] = fmaf(pw0, __uint_as_float(php0.y & 0xffff0000u), ahi[1]);
      alo[2] = fmaf(pw0, __uint_as_float(php0.z << 16),         alo[2]);
      ahi[2] = fmaf(pw0, __uint_as_float(php0.z & 0xffff0000u), ahi[2]);
      alo[3] = fmaf(pw0, __uint_as_float(php0.w << 16),         alo[3]);
      ahi[3] = fmaf(pw0, __uint_as_float(php0.w & 0xffff0000u), ahi[3]);
      den += pw0;
      alo[0] = fmaf(pw1, __uint_as_float(php1.x << 16),         alo[0]);
      ahi[0] = fmaf(pw1, __uint_as_float(php1.x & 0xffff0000u), ahi[0]);
      alo[1] = fmaf(pw1, __uint_as_float(php1.y << 16),         alo[1]);
      ahi[1] = fmaf(pw1, __uint_as_float(php1.y & 0xffff0000u), ahi[1]);
      alo[2] = fmaf(pw1, __uint_as_float(php1.z << 16),         alo[2]);
      ahi[2] = fmaf(pw1, __uint_as_float(php1.z & 0xffff0000u), ahi[2]);
      alo[3] = fmaf(pw1, __uint_as_float(php1.w << 16),         alo[3]);
      ahi[3] = fmaf(pw1, __uint_as_float(php1.w & 0xffff0000u), ahi[3]);
      den += pw1;
    }

    // issue NEXT node's trip-1 before this node's tail + finalize
    if (q < 7) {
      mcur = lcnt[dl + 1]; if (mcur > CAP) mcur = CAP;
      prefetch(dl + 1, mcur, pw0, pw1, php0, php1);
    }

    // tail trips (m > 16)
    for (int j = 16; j < m; j += 16) {
      int idx0 = j + grp8;
      int idx1 = j + 8 + grp8;
      int ci0 = idx0 < m ? idx0 : m - 1;
      int ci1 = idx1 < m ? idx1 : m - 1;
      unsigned u0 = rec[dl * CAP + ci0];
      unsigned u1 = rec[dl * CAP + ci1];
      float w0 = __uint_as_float(u0 & 0xffff0000u);
      float w1 = __uint_as_float(u1 & 0xffff0000u);
      if (idx0 >= m) w0 = 0.f;
      if (idx1 >= m) w1 = 0.f;
      int s0 = (int)(u0 & 0xffffu);
      int s1 = (int)(u1 & 0xffffu);
      uint4 hp0 = *(const uint4*)(hbf + (long)s0 * 32 + ql8 * 4);
      uint4 hp1 = *(const uint4*)(hbf + (long)s1 * 32 + ql8 * 4);
      alo[0] = fmaf(w0, __uint_as_float(hp0.x << 16),         alo[0]);
      ahi[0] = fmaf(w0, __uint_as_float(hp0.x & 0xffff0000u), ahi[0]);
      alo[1] = fmaf(w0, __uint_as_float(hp0.y << 16),         alo[1]);
      ahi[1] = fmaf(w0, __uint_as_float(hp0.y & 0xffff0000u), ahi[1]);
      alo[2] = fmaf(w0, __uint_as_float(hp0.z << 16),         alo[2]);
      ahi[2] = fmaf(w0, __uint_as_float(hp0.z & 0xffff0000u), ahi[2]);
      alo[3] = fmaf(w0, __uint_as_float(hp0.w << 16),         alo[3]);
      ahi[3] = fmaf(w0, __uint_as_float(hp0.w & 0xffff0000u), ahi[3]);
      den += w0;
      alo[0] = fmaf(w1, __uint_as_float(hp1.x << 16),         alo[0]);
      ahi[0] = fmaf(w1, __uint_as_float(hp1.x & 0xffff0000u), ahi[0]);
      alo[1] = fmaf(w1, __uint_as_float(hp1.y << 16),         alo[1]);
      ahi[1] = fmaf(w1, __uint_as_float(hp1.y & 0xffff0000u), ahi[1]);
      alo[2] = fmaf(w1, __uint_as_float(hp1.z << 16),         alo[2]);
      ahi[2] = fmaf(w1, __uint_as_float(hp1.z & 0xffff0000u), ahi[2]);
      alo[3] = fmaf(w1, __uint_as_float(hp1.w << 16),         alo[3]);
      ahi[3] = fmaf(w1, __uint_as_float(hp1.w & 0xffff0000u), ahi[3]);
      den += w1;
    }

    // combine the 8 groups (lanes sharing lane&7 hold the same dims)
    #pragma unroll
    for (int mm = 8; mm <= 32; mm <<= 1) {
      #pragma unroll
      for (int c = 0; c < 4; ++c) {
        alo[c] += __shfl_xor(alo[c], mm, 64);
        ahi[c] += __shfl_xor(ahi[c], mm, 64);
      }
      den += __shfl_xor(den, mm, 64);
    }

    // finalize h for this node: lanes 0-7 each own 8 dims (no transpose)
    if (grp8 == 0) {
      float inv = den > 0.f ? 1.0f / den : 0.f;  // empty segment -> bias only
      float4 hlo, hhi;
      hlo.x = fmaxf(fmaf(alo[0], inv, bcl[0]), 0.f);
      hlo.y = fmaxf(fmaf(alo[1], inv, bcl[1]), 0.f);
      hlo.z = fmaxf(fmaf(alo[2], inv, bcl[2]), 0.f);
      hlo.w = fmaxf(fmaf(alo[3], inv, bcl[3]), 0.f);
      hhi.x = fmaxf(fmaf(ahi[0], inv, bch[0]), 0.f);
      hhi.y = fmaxf(fmaf(ahi[1], inv, bch[1]), 0.f);
      hhi.z = fmaxf(fmaf(ahi[2], inv, bch[2]), 0.f);
      hhi.w = fmaxf(fmaf(ahi[3], inv, bch[3]), 0.f);
      *(float4*)(&hl[dl * 68 + ql8 * 4])      = hlo;
      *(float4*)(&hl[dl * 68 + 32 + ql8 * 4]) = hhi;
    }
  }
  __syncthreads();

  // MFMA epilogue: waves 0/1 compute out[32, 64] = h @ W_lin + b_lin
  if (wv < 2) {
    f32x16 acc;
    #pragma unroll
    for (int i = 0; i < 16; ++i) acc[i] = 0.f;
    const int mrow  = lane & 31;
    const int khalf = (lane >> 5) * 8;
    #pragma unroll
    for (int s = 0; s < 4; ++s) {
      float4 va = *(const float4*)(&hl[mrow * 68 + s * 16 + khalf]);
      float4 vb = *(const float4*)(&hl[mrow * 68 + s * 16 + khalf + 4]);
      s16x8 a;
      a[0] = f2bf(va.x); a[1] = f2bf(va.y); a[2] = f2bf(va.z); a[3] = f2bf(va.w);
      a[4] = f2bf(vb.x); a[5] = f2bf(vb.y); a[6] = f2bf(vb.z); a[7] = f2bf(vb.w);
      s16x8 b = *(const s16x8*)(wlf + ((s * 2 + wv) * 64 + lane) * 8);
      acc = __builtin_amdgcn_mfma_f32_32x32x16_bf16(a, b, acc, 0, 0, 0);
    }
    const int col  = (lane & 31) + 32 * wv;
    const float blv = b_lin[col];
    const int rbase = 4 * (lane >> 5);
    #pragma unroll
    for (int r = 0; r < 16; ++r) {
      int row = (r & 3) + 8 * (r >> 2) + rbase;
      int n = nb + row;
      if (n < N_NODES) out[(long)n * DIM_H + col] = acc[r] + blv;
    }
  }
}

// ---------------------------------------------------------------------------
// Workspace: hbf 6.4 MB | a_src/a_dst 0.4 MB | gbc 8 KB | binbuf 4.8 MB
// ~= 11.6 MB — well under the provided ws.
// ---------------------------------------------------------------------------
extern "C" void kernel_launch(void* const* d_in, const int* in_sizes, int n_in,
                              void* d_out, int out_size, void* d_ws, size_t ws_size,
                              hipStream_t stream) {
  const float* x        = (const float*)d_in[0];
  const int*   ei       = (const int*)d_in[1];
  const float* Wsrc     = (const float*)d_in[2];
  const float* Wdst     = (const float*)d_in[3];
  const float* att_src  = (const float*)d_in[4];
  const float* att_dst  = (const float*)d_in[5];
  const float* bias_cv  = (const float*)d_in[6];
  const float* W_lin    = (const float*)d_in[7];
  const float* b_lin    = (const float*)d_in[8];
  float* out = (float*)d_out;

  unsigned* hbf    = (unsigned*)d_ws;           // N*32 u32 (6.4 MB)
  float*    a_src  = (float*)(hbf + 1600000);   // NPAD f32
  float*    a_dst  = a_src + NPAD;              // NPAD f32
  int*      gbc    = (int*)(a_dst + NPAD);      // 2048 i32 fine-bucket cursors
  unsigned* binbuf = (unsigned*)(gbc + 2048);   // NBUK2*BCAP2 u32 (4.8 MB)

  hipMemsetAsync(gbc, 0, 2048 * sizeof(int), stream);

  proj_binA_kernel<<<PBLKS + ABLKS, 512, 0, stream>>>(
      x, Wsrc, Wdst, att_src, att_dst, ei, hbf, a_src, a_dst, gbc, binbuf);

  gatherfused_kernel<<<NBUK2, 256, 0, stream>>>(
      binbuf, gbc, a_src, a_dst, hbf, bias_cv, W_lin, b_lin, out);
}

// Round 13
// 154.576 us; speedup vs baseline: 1.0714x; 1.0127x over previous
//
#include <hip/hip_runtime.h>
#include <math.h>

#define N_NODES 50000
#define N_EDGES 800000
#define IN_FEAT 256
#define DIM_H   64
#define NPAD    50176   // padded N slots; 50176 = 392 * 128
#define CAP     48      // per-node capacity; Poisson(16) max deg ~40 << 48
#define NBUK2   1568    // fine dst buckets (32 nodes each)
#define BCAP2   768     // fine-bucket capacity; mean 510, >11 sigma headroom
#define EPB     4096    // edges per binA block
#define PBLKS   392     // proj blocks = 50176/128 (128 rows/block, 8 waves)
#define ABLKS   196     // binA blocks  = ceil(E/EPB)
#define PNODES  32      // nodes per gather block (= fine bucket size)

typedef __attribute__((ext_vector_type(8)))  short  s16x8;   // 8 bf16 (4 VGPRs)
typedef __attribute__((ext_vector_type(16))) float  f32x16;  // MFMA 32x32 acc

__device__ __forceinline__ short f2bf(float f) {   // RNE f32->bf16
  unsigned u = __float_as_uint(f);
  u += 0x7fffu + ((u >> 16) & 1u);
  return (short)(u >> 16);
}

// ---------------------------------------------------------------------------
// proj_binA r13 = r12 + T14 issue-early x-loads.
// r12 counters: proj flat at ~42.5us, VGPR only 48, Occ 24% — the x-loads
// (the kernel's bulk traffic) were issued AFTER the W-prologue barrier and
// their ~900cyc HBM latency was exposed (48-VGPR budget keeps few in
// flight). Fix: issue all 16 x float4 into registers BEFORE the W staging;
// __syncthreads' fence semantics pin them there, so the ~128KB W prologue
// (L2 reads + 16K converts + LDS stores) covers the load latency and the
// MFMA loop starts with x already in registers. Costs 64 VGPR of liveness
// across the prologue (pred. total ~110-125 < 128 cap).
// Distinct from r1 (loads after the same barrier - compiler-equivalent) and
// r9 (added redundant per-wave converts, not just liveness).
// Everything else identical to r12 (512-thr blocks, XOR-swizzled staging,
// K-half combine, fine-bucket binA).
// ---------------------------------------------------------------------------
__global__ __launch_bounds__(512, 4) void proj_binA_kernel(
    const float* __restrict__ x,
    const float* __restrict__ Wsrc,
    const float* __restrict__ Wdst,
    const float* __restrict__ att_src,
    const float* __restrict__ att_dst,
    const int* __restrict__ ei,
    unsigned* __restrict__ hbf,
    float* __restrict__ a_src,
    float* __restrict__ a_dst,
    int* __restrict__ gbc,
    unsigned* __restrict__ binbuf) {
  __shared__ float fa[9344];                 // 37.4 KB: wfrag overlay / combine / binA hist
  __shared__ float wdl[IN_FEAT];             // W_dst @ att_dst
  __shared__ float attl[DIM_H];

  short* const wfrag = (short*)fa;           // 16384 bf16 = first 8192 f32 words
  const int tid = threadIdx.x;

  // ---------------- binA role ----------------
  if (blockIdx.x >= PBLKS) {
    int* bcnt = (int*)fa;             // overlay: NBUK2 ints
    int* wcur = bcnt + NBUK2;         // overlay: NBUK2 ints (12.5 KB < 37.4 KB)
    const int e0 = (blockIdx.x - PBLKS) * EPB;

    for (int b = tid; b < NBUK2; b += 512) bcnt[b] = 0;
    __syncthreads();

    int dst[8];
    #pragma unroll
    for (int i = 0; i < 8; ++i) {
      int e = e0 + tid + 512 * i;
      dst[i] = (e < N_EDGES) ? ei[N_EDGES + e] : -1;
      if (dst[i] >= 0) atomicAdd(&bcnt[dst[i] >> 5], 1);
    }
    __syncthreads();

    for (int b = tid; b < NBUK2; b += 512) {
      int c = bcnt[b];
      wcur[b] = c ? atomicAdd(&gbc[b], c) : 0;
    }
    __syncthreads();

    #pragma unroll
    for (int i = 0; i < 8; ++i) {
      int e = e0 + tid + 512 * i;
      if (e < N_EDGES) {
        int s = ei[e];
        int b = dst[i] >> 5;
        int pos = atomicAdd(&wcur[b], 1);
        if (pos < BCAP2)
          binbuf[(long)b * BCAP2 + pos] =
              (unsigned)s | ((unsigned)(dst[i] & 31) << 16);
      }
    }
    return;
  }

  // ---------------- proj role ----------------
  const int lane = tid & 63;
  const int wv   = tid >> 6;    // 0..7
  const int tile = wv >> 1;     // which 32-row tile of the block's 128 rows
  const int h    = wv & 1;      // K-half: h=0 -> k 0..127, h=1 -> k 128..255

  const int base  = blockIdx.x * 128 + tile * 32;
  int row = base + (lane & 31); if (row > N_NODES - 1) row = N_NODES - 1;
  const int koff8 = (lane >> 5) * 8;
  const int k0    = h * 128;
  const float* px = x + (long)row * IN_FEAT + k0 + koff8;

  // T14: issue ALL x loads before the W prologue. The barriers below are
  // fences, so these cannot sink; their HBM latency hides under the W work.
  float4 xa[8], xb[8];
  #pragma unroll
  for (int s = 0; s < 8; ++s) {
    xa[s] = *(const float4*)(px + s * 16);
    xb[s] = *(const float4*)(px + s * 16 + 4);
  }

  if (tid < DIM_H) attl[tid] = att_dst[tid];
  __syncthreads();

  if (tid < IN_FEAT) {
    float s = 0.f;
    const float4* wrow = (const float4*)(Wdst + (long)tid * DIM_H);
    #pragma unroll
    for (int q = 0; q < 16; ++q) {
      float4 r = wrow[q];
      s = fmaf(r.x, attl[4 * q + 0], s);
      s = fmaf(r.y, attl[4 * q + 1], s);
      s = fmaf(r.z, attl[4 * q + 2], s);
      s = fmaf(r.w, attl[4 * q + 3], s);
    }
    wdl[tid] = s;
  }

  // stage W_src into B-frag order, float4-vectorized, XOR-swizzled slots.
  // element i of the float4 -> slot sidx+i -> byte sw ^ (i<<4)
  for (int e4 = tid * 4; e4 < IN_FEAT * DIM_H; e4 += 2048) {
    float4 w4 = *(const float4*)(Wsrc + e4);
    int k = e4 >> 6, n0 = e4 & 63;
    int s = k >> 4, half = (k >> 3) & 1, j = k & 7, t = n0 >> 5;
    int fl0  = (n0 & 31) + 32 * half;
    int sidx = (s * 2 + t) * 64 + fl0;
    int sw   = (sidx << 4) ^ ((sidx & 56) << 1);   // swizzled byte offset
    ((short*)((char*)wfrag + (sw ^  0)))[j] = f2bf(w4.x);
    ((short*)((char*)wfrag + (sw ^ 16)))[j] = f2bf(w4.y);
    ((short*)((char*)wfrag + (sw ^ 32)))[j] = f2bf(w4.z);
    ((short*)((char*)wfrag + (sw ^ 48)))[j] = f2bf(w4.w);
  }
  __syncthreads();

  const int swl = (lane & 56) << 1;   // reader XOR mask (slot&56 == lane&56)

  f32x16 acc0, acc1;
  #pragma unroll
  for (int i = 0; i < 16; ++i) { acc0[i] = 0.f; acc1[i] = 0.f; }
  float pd = 0.f;

  #pragma unroll
  for (int s = 0; s < 8; ++s) {
    float4 va = xa[s];
    float4 vb = xb[s];
    const float* wp = wdl + k0 + s * 16 + koff8;
    float4 w1 = *(const float4*)(wp);
    float4 w2 = *(const float4*)(wp + 4);
    pd = fmaf(va.x, w1.x, pd); pd = fmaf(va.y, w1.y, pd);
    pd = fmaf(va.z, w1.z, pd); pd = fmaf(va.w, w1.w, pd);
    pd = fmaf(vb.x, w2.x, pd); pd = fmaf(vb.y, w2.y, pd);
    pd = fmaf(vb.z, w2.z, pd); pd = fmaf(vb.w, w2.w, pd);
    s16x8 a;
    a[0] = f2bf(va.x); a[1] = f2bf(va.y); a[2] = f2bf(va.z); a[3] = f2bf(va.w);
    a[4] = f2bf(vb.x); a[5] = f2bf(vb.y); a[6] = f2bf(vb.z); a[7] = f2bf(vb.w);
    const int f = (h * 8 + s) * 2;
    const int si0 = (f + 0) * 64 + lane;
    const int si1 = (f + 1) * 64 + lane;
    s16x8 b0 = *(const s16x8*)((const char*)wfrag + ((si0 << 4) ^ swl));
    s16x8 b1 = *(const s16x8*)((const char*)wfrag + ((si1 << 4) ^ swl));
    acc0 = __builtin_amdgcn_mfma_f32_32x32x16_bf16(a, b0, acc0, 0, 0, 0);
    acc1 = __builtin_amdgcn_mfma_f32_32x32x16_bf16(a, b1, acc1, 0, 0, 0);
  }
  float pds = pd + __shfl_xor(pd, 32, 64);   // lanes<32: row-sum over this K-half

  // ---- K-half combine via fa (wfrag dead after MFMA loop) ----
  __syncthreads();
  float* myslot = fa + tile * 2304 + lane * 36;   // stride 36 words: 8-round b128 floor
  float* pdb    = fa + 9216 + tile * 32;          // 4x32 f32 partial a_dst

  if (h == 1) {
    #pragma unroll
    for (int i = 0; i < 4; ++i)
      *(float4*)(myslot + i * 4) =
          make_float4(acc0[4 * i], acc0[4 * i + 1], acc0[4 * i + 2], acc0[4 * i + 3]);
    #pragma unroll
    for (int i = 0; i < 4; ++i)
      *(float4*)(myslot + 16 + i * 4) =
          make_float4(acc1[4 * i], acc1[4 * i + 1], acc1[4 * i + 2], acc1[4 * i + 3]);
    if (lane < 32) pdb[lane] = pds;
  }
  __syncthreads();
  if (h == 1) return;

  #pragma unroll
  for (int i = 0; i < 4; ++i) {
    float4 t = *(const float4*)(myslot + i * 4);
    acc0[4 * i] += t.x; acc0[4 * i + 1] += t.y;
    acc0[4 * i + 2] += t.z; acc0[4 * i + 3] += t.w;
  }
  #pragma unroll
  for (int i = 0; i < 4; ++i) {
    float4 t = *(const float4*)(myslot + 16 + i * 4);
    acc1[4 * i] += t.x; acc1[4 * i + 1] += t.y;
    acc1[4 * i + 2] += t.z; acc1[4 * i + 3] += t.w;
  }
  pds += pdb[lane & 31];

  // ---- epilogue (h=0 waves only; full-K accumulators) ----
  const int col = lane & 31;
  const int rhi = 4 * (lane >> 5);

  #pragma unroll
  for (int r = 0; r < 16; ++r) {
    int node = base + (r & 3) + 8 * (r >> 2) + rhi;
    if (node < N_NODES) {
      unsigned p = (unsigned)(unsigned short)f2bf(acc0[r]) |
                   ((unsigned)(unsigned short)f2bf(acc1[r]) << 16);
      hbf[(long)node * 32 + col] = p;
    }
  }

  float att0 = att_src[col];
  float att1 = att_src[col + 32];
  #pragma unroll
  for (int r = 0; r < 16; ++r) {
    float t = acc0[r] * att0 + acc1[r] * att1;
    t += __shfl_xor(t, 1, 64);
    t += __shfl_xor(t, 2, 64);
    t += __shfl_xor(t, 4, 64);
    t += __shfl_xor(t, 8, 64);
    t += __shfl_xor(t, 16, 64);
    int node = base + (r & 3) + 8 * (r >> 2) + rhi;
    if (col == 0 && node < N_NODES) a_src[node] = t;
  }

  int node = base + (lane & 31);
  if (lane < 32 && node < N_NODES) a_dst[node] = pds;
}

// ---------------------------------------------------------------------------
// gatherfused: IDENTICAL to round-7/r11/r12 (MFMA epilogue version, verified
// WIN, <41.5 us) — frozen so the proj change is cleanly attributable.
// ---------------------------------------------------------------------------
__global__ __launch_bounds__(256) void gatherfused_kernel(
    const unsigned* __restrict__ binbuf,
    const int* __restrict__ gbc,
    const float* __restrict__ a_src,
    const float* __restrict__ a_dst,
    const unsigned* __restrict__ hbf,
    const float* __restrict__ bias_conv,
    const float* __restrict__ W_lin,
    const float* __restrict__ b_lin,
    float* __restrict__ out) {
  __shared__ unsigned rec[PNODES * CAP];   // {bf16(w):16 | src:16}, 6 KB
  __shared__ int   lcnt[PNODES];
  __shared__ float adl[PNODES];
  __shared__ short wlf[4096];              // W_lin B-frags bf16, 8 KB
  __shared__ float hl[PNODES * 68];        // h[32][64] padded stride 68, 8.5 KB

  const int tid    = threadIdx.x;
  const int bucket = blockIdx.x;           // fine bucket = this block's 32 nodes
  const int nb     = bucket * PNODES;      // first node

  // stage W_lin into B-frag order (bf16)
  for (int e4 = tid * 4; e4 < DIM_H * DIM_H; e4 += 1024) {
    float4 w4 = *(const float4*)(W_lin + e4);
    int k = e4 >> 6, n0 = e4 & 63;
    int s = k >> 4, half = (k >> 3) & 1, j = k & 7, t = n0 >> 5;
    short* p = &wlf[((s * 2 + t) * 64 + ((n0 & 31) + 32 * half)) * 8 + j];
    p[0]  = f2bf(w4.x);
    p[8]  = f2bf(w4.y);
    p[16] = f2bf(w4.z);
    p[24] = f2bf(w4.w);
  }
  if (tid < PNODES) {
    lcnt[tid] = 0;
    adl[tid]  = a_dst[nb + tid];   // nodes >= N_NODES never referenced
  }
  __syncthreads();

  // phase 1: bin this bucket's edges into LDS
  int count = gbc[bucket]; if (count > BCAP2) count = BCAP2;
  const unsigned* bb = binbuf + (long)bucket * BCAP2;
  for (int i = tid; i < count; i += 256) {
    unsigned u = bb[i];
    int dl = (int)(u >> 16);               // 0..31
    int s  = (int)(u & 0xffffu);
    float sc = a_src[s] + adl[dl];
    sc = sc >= 0.f ? sc : 0.2f * sc;       // leaky_relu 0.2
    float w = __expf(sc);
    int pos = atomicAdd(&lcnt[dl], 1);
    if (pos < CAP)                         // never fires (maxdeg << CAP)
      rec[dl * CAP + pos] =
          ((unsigned)(unsigned short)f2bf(w) << 16) | (u & 0xffffu);
  }
  __syncthreads();

  // phase 2: gather, pipelined across the wave's 8 nodes
  const int lane = tid & 63;
  const int wv   = __builtin_amdgcn_readfirstlane(tid >> 6);
  const int grp8 = lane >> 3;
  const int ql8  = lane & 7;

  float bcl[4], bch[4];
  #pragma unroll
  for (int c = 0; c < 4; ++c) {
    bcl[c] = bias_conv[ql8 * 4 + c];
    bch[c] = bias_conv[32 + ql8 * 4 + c];
  }

  auto prefetch = [&](int dl, int m_, float& W0, float& W1, uint4& HP0, uint4& HP1) {
    if (m_ > 0) {
      int i0 = (grp8     < m_) ? grp8     : m_ - 1;
      int i1 = (8 + grp8 < m_) ? 8 + grp8 : m_ - 1;
      unsigned u0 = rec[dl * CAP + i0];
      unsigned u1 = rec[dl * CAP + i1];
      W0 = (grp8     < m_) ? __uint_as_float(u0 & 0xffff0000u) : 0.f;
      W1 = (8 + grp8 < m_) ? __uint_as_float(u1 & 0xffff0000u) : 0.f;
      HP0 = *(const uint4*)(hbf + (long)(u0 & 0xffffu) * 32 + ql8 * 4);
      HP1 = *(const uint4*)(hbf + (long)(u1 & 0xffffu) * 32 + ql8 * 4);
    } else {
      W0 = 0.f; W1 = 0.f;
      HP0 = make_uint4(0u, 0u, 0u, 0u);
      HP1 = make_uint4(0u, 0u, 0u, 0u);
    }
  };

  int mcur = lcnt[wv * 8]; if (mcur > CAP) mcur = CAP;
  float pw0, pw1; uint4 php0, php1;
  prefetch(wv * 8, mcur, pw0, pw1, php0, php1);

  #pragma unroll
  for (int q = 0; q < 8; ++q) {
    const int dl = wv * 8 + q;
    const int m  = mcur;

    float alo[4] = {0.f, 0.f, 0.f, 0.f};
    float ahi[4] = {0.f, 0.f, 0.f, 0.f};
    float den = 0.f;

    // consume prefetched trip 1
    {
      alo[0] = fmaf(pw0, __uint_as_float(php0.x << 16),         alo[0]);
      ahi[0] = fmaf(pw0, __uint_as_float(php0.x & 0xffff0000u), ahi[0]);
      alo[1] = fmaf(pw0, __uint_as_float(php0.y << 16),         alo[1]);
      ahi[1] = fmaf(pw0, __uint_as_float(php0.y & 0xffff0000u), ahi[1]);
      alo[2] = fmaf(pw0, __uint_as_float(php0.z << 16),         alo[2]);
      ahi[2] = fmaf(pw0, __uint_as_float(php0.z & 0xffff0000u), ahi[2]);
      alo[3] = fmaf(pw0, __uint_as_float(php0.w << 16),         alo[3]);
      ahi[3] = fmaf(pw0, __uint_as_float(php0.w & 0xffff0000u), ahi[3]);
      den += pw0;
      alo[0] = fmaf(pw1, __uint_as_float(php1.x << 16),         alo[0]);
      ahi[0] = fmaf(pw1, __uint_as_float(php1.x & 0xffff0000u), ahi[0]);
      alo[1] = fmaf(pw1, __uint_as_float(php1.y << 16),         alo[1]);
      ahi[1] = fmaf(pw1, __uint_as_float(php1.y & 0xffff0000u), ahi[1]);
      alo[2] = fmaf(pw1, __uint_as_float(php1.z << 16),         alo[2]);
      ahi[2] = fmaf(pw1, __uint_as_float(php1.z & 0xffff0000u), ahi[2]);
      alo[3] = fmaf(pw1, __uint_as_float(php1.w << 16),         alo[3]);
      ahi[3] = fmaf(pw1, __uint_as_float(php1.w & 0xffff0000u), ahi[3]);
      den += pw1;
    }

    // issue NEXT node's trip-1 before this node's tail + finalize
    if (q < 7) {
      mcur = lcnt[dl + 1]; if (mcur > CAP) mcur = CAP;
      prefetch(dl + 1, mcur, pw0, pw1, php0, php1);
    }

    // tail trips (m > 16)
    for (int j = 16; j < m; j += 16) {
      int idx0 = j + grp8;
      int idx1 = j + 8 + grp8;
      int ci0 = idx0 < m ? idx0 : m - 1;
      int ci1 = idx1 < m ? idx1 : m - 1;
      unsigned u0 = rec[dl * CAP + ci0];
      unsigned u1 = rec[dl * CAP + ci1];
      float w0 = __uint_as_float(u0 & 0xffff0000u);
      float w1 = __uint_as_float(u1 & 0xffff0000u);
      if (idx0 >= m) w0 = 0.f;
      if (idx1 >= m) w1 = 0.f;
      int s0 = (int)(u0 & 0xffffu);
      int s1 = (int)(u1 & 0xffffu);
      uint4 hp0 = *(const uint4*)(hbf + (long)s0 * 32 + ql8 * 4);
      uint4 hp1 = *(const uint4*)(hbf + (long)s1 * 32 + ql8 * 4);
      alo[0] = fmaf(w0, __uint_as_float(hp0.x << 16),         alo[0]);
      ahi[0] = fmaf(w0, __uint_as_float(hp0.x & 0xffff0000u), ahi[0]);
      alo[1] = fmaf(w0, __uint_as_float(hp0.y << 16),         alo[1]);
      ahi[1] = fmaf(w0, __uint_as_float(hp0.y & 0xffff0000u), ahi[1]);
      alo[2] = fmaf(w0, __uint_as_float(hp0.z << 16),         alo[2]);
      ahi[2] = fmaf(w0, __uint_as_float(hp0.z & 0xffff0000u), ahi[2]);
      alo[3] = fmaf(w0, __uint_as_float(hp0.w << 16),         alo[3]);
      ahi[3] = fmaf(w0, __uint_as_float(hp0.w & 0xffff0000u), ahi[3]);
      den += w0;
      alo[0] = fmaf(w1, __uint_as_float(hp1.x << 16),         alo[0]);
      ahi[0] = fmaf(w1, __uint_as_float(hp1.x & 0xffff0000u), ahi[0]);
      alo[1] = fmaf(w1, __uint_as_float(hp1.y << 16),         alo[1]);
      ahi[1] = fmaf(w1, __uint_as_float(hp1.y & 0xffff0000u), ahi[1]);
      alo[2] = fmaf(w1, __uint_as_float(hp1.z << 16),         alo[2]);
      ahi[2] = fmaf(w1, __uint_as_float(hp1.z & 0xffff0000u), ahi[2]);
      alo[3] = fmaf(w1, __uint_as_float(hp1.w << 16),         alo[3]);
      ahi[3] = fmaf(w1, __uint_as_float(hp1.w & 0xffff0000u), ahi[3]);
      den += w1;
    }

    // combine the 8 groups (lanes sharing lane&7 hold the same dims)
    #pragma unroll
    for (int mm = 8; mm <= 32; mm <<= 1) {
      #pragma unroll
      for (int c = 0; c < 4; ++c) {
        alo[c] += __shfl_xor(alo[c], mm, 64);
        ahi[c] += __shfl_xor(ahi[c], mm, 64);
      }
      den += __shfl_xor(den, mm, 64);
    }

    // finalize h for this node: lanes 0-7 each own 8 dims (no transpose)
    if (grp8 == 0) {
      float inv = den > 0.f ? 1.0f / den : 0.f;  // empty segment -> bias only
      float4 hlo, hhi;
      hlo.x = fmaxf(fmaf(alo[0], inv, bcl[0]), 0.f);
      hlo.y = fmaxf(fmaf(alo[1], inv, bcl[1]), 0.f);
      hlo.z = fmaxf(fmaf(alo[2], inv, bcl[2]), 0.f);
      hlo.w = fmaxf(fmaf(alo[3], inv, bcl[3]), 0.f);
      hhi.x = fmaxf(fmaf(ahi[0], inv, bch[0]), 0.f);
      hhi.y = fmaxf(fmaf(ahi[1], inv, bch[1]), 0.f);
      hhi.z = fmaxf(fmaf(ahi[2], inv, bch[2]), 0.f);
      hhi.w = fmaxf(fmaf(ahi[3], inv, bch[3]), 0.f);
      *(float4*)(&hl[dl * 68 + ql8 * 4])      = hlo;
      *(float4*)(&hl[dl * 68 + 32 + ql8 * 4]) = hhi;
    }
  }
  __syncthreads();

  // MFMA epilogue: waves 0/1 compute out[32, 64] = h @ W_lin + b_lin
  if (wv < 2) {
    f32x16 acc;
    #pragma unroll
    for (int i = 0; i < 16; ++i) acc[i] = 0.f;
    const int mrow  = lane & 31;
    const int khalf = (lane >> 5) * 8;
    #pragma unroll
    for (int s = 0; s < 4; ++s) {
      float4 va = *(const float4*)(&hl[mrow * 68 + s * 16 + khalf]);
      float4 vb = *(const float4*)(&hl[mrow * 68 + s * 16 + khalf + 4]);
      s16x8 a;
      a[0] = f2bf(va.x); a[1] = f2bf(va.y); a[2] = f2bf(va.z); a[3] = f2bf(va.w);
      a[4] = f2bf(vb.x); a[5] = f2bf(vb.y); a[6] = f2bf(vb.z); a[7] = f2bf(vb.w);
      s16x8 b = *(const s16x8*)(wlf + ((s * 2 + wv) * 64 + lane) * 8);
      acc = __builtin_amdgcn_mfma_f32_32x32x16_bf16(a, b, acc, 0, 0, 0);
    }
    const int col  = (lane & 31) + 32 * wv;
    const float blv = b_lin[col];
    const int rbase = 4 * (lane >> 5);
    #pragma unroll
    for (int r = 0; r < 16; ++r) {
      int row = (r & 3) + 8 * (r >> 2) + rbase;
      int n = nb + row;
      if (n < N_NODES) out[(long)n * DIM_H + col] = acc[r] + blv;
    }
  }
}

// ---------------------------------------------------------------------------
// Workspace: hbf 6.4 MB | a_src/a_dst 0.4 MB | gbc 8 KB | binbuf 4.8 MB
// ~= 11.6 MB — well under the provided ws.
// ---------------------------------------------------------------------------
extern "C" void kernel_launch(void* const* d_in, const int* in_sizes, int n_in,
                              void* d_out, int out_size, void* d_ws, size_t ws_size,
                              hipStream_t stream) {
  const float* x        = (const float*)d_in[0];
  const int*   ei       = (const int*)d_in[1];
  const float* Wsrc     = (const float*)d_in[2];
  const float* Wdst     = (const float*)d_in[3];
  const float* att_src  = (const float*)d_in[4];
  const float* att_dst  = (const float*)d_in[5];
  const float* bias_cv  = (const float*)d_in[6];
  const float* W_lin    = (const float*)d_in[7];
  const float* b_lin    = (const float*)d_in[8];
  float* out = (float*)d_out;

  unsigned* hbf    = (unsigned*)d_ws;           // N*32 u32 (6.4 MB)
  float*    a_src  = (float*)(hbf + 1600000);   // NPAD f32
  float*    a_dst  = a_src + NPAD;              // NPAD f32
  int*      gbc    = (int*)(a_dst + NPAD);      // 2048 i32 fine-bucket cursors
  unsigned* binbuf = (unsigned*)(gbc + 2048);   // NBUK2*BCAP2 u32 (4.8 MB)

  hipMemsetAsync(gbc, 0, 2048 * sizeof(int), stream);

  proj_binA_kernel<<<PBLKS + ABLKS, 512, 0, stream>>>(
      x, Wsrc, Wdst, att_src, att_dst, ei, hbf, a_src, a_dst, gbc, binbuf);

  gatherfused_kernel<<<NBUK2, 256, 0, stream>>>(
      binbuf, gbc, a_src, a_dst, hbf, bias_cv, W_lin, b_lin, out);
}